// Round 7
// baseline (659.286 us; speedup 1.0000x reference)
//
#include <hip/hip_runtime.h>
#include <hip/hip_bf16.h>

typedef unsigned short u16;
typedef unsigned int u32;
typedef __attribute__((ext_vector_type(8))) short short8;
typedef __attribute__((ext_vector_type(4))) float f32x4;

#define B_ 4
#define T_ 2048
#define D_ 1024
#define H_ 16
#define HS_ 64
#define BT (B_*T_)

__device__ __forceinline__ float bf2f(u16 b){ union{u32 u; float f;} v; v.u=((u32)b)<<16; return v.f; }
__device__ __forceinline__ u16 f2bf(float f){
    __hip_bfloat16 h = __float2bfloat16(f);
    union{__hip_bfloat16 h; u16 u;} v; v.h = h; return v.u;
}
// split f32 into hi/lo bf16: x ~= hi + lo
__device__ __forceinline__ void split2(float x, u16& h, u16& l){
    u16 hb = f2bf(x);
    float fh = bf2f(hb);
    h = hb; l = f2bf(x - fh);
}
union U4 { u16 s[4]; uint2 v; };
union S8 { u16 s[8]; short8 v; };

// async global->LDS, 16B per lane; LDS dest wave-linear (base + lane*16)
#define GLD16(g,l) __builtin_amdgcn_global_load_lds( \
    (__attribute__((address_space(1))) void*)(u16*)(g), \
    (__attribute__((address_space(3))) void*)(l), 16, 0, 0)

// XOR-swizzled offset into a row-major [R][64]-u16 LDS tile, 16B-chunk granularity.
__device__ __forceinline__ int swz(int row, int col){
    return row*64 + (((col>>3) ^ (row&7))<<3) + (col&7);
}
// chunk-swizzle for the GEMM [128][32]-u16 tiles (64B rows, 4 x 16B chunks).
// Proven: SQ_LDS_BANK_CONFLICT 12.6M -> 0 (round 4).
#define FCHK(r) (((r)>>1)&3)

// DPP cross-lane move within a 16-lane row
#define DPPMV(x, ctrl) __int_as_float(__builtin_amdgcn_update_dpp(0, __float_as_int(x), (ctrl), 0xF, 0xF, true))

// ---- grid-stride f32 -> (hi,lo) bf16 split, 8 elems/thread/iter ----
__global__ __launch_bounds__(256) void split_f32(const float* __restrict__ src,
                                                 u16* __restrict__ dh, u16* __restrict__ dl,
                                                 int n8)
{
    int i = blockIdx.x*256 + threadIdx.x;
    const int stride = gridDim.x*256;
    for (; i < n8; i += stride){
        float4 a = *(const float4*)(src + (size_t)i*8);
        float4 b = *(const float4*)(src + (size_t)i*8 + 4);
        S8 hh, ll;
        split2(a.x, hh.s[0], ll.s[0]); split2(a.y, hh.s[1], ll.s[1]);
        split2(a.z, hh.s[2], ll.s[2]); split2(a.w, hh.s[3], ll.s[3]);
        split2(b.x, hh.s[4], ll.s[4]); split2(b.y, hh.s[5], ll.s[5]);
        split2(b.z, hh.s[6], ll.s[6]); split2(b.w, hh.s[7], ll.s[7]);
        *(short8*)(dh + (size_t)i*8) = hh.v;
        *(short8*)(dl + (size_t)i*8) = ll.v;
    }
}

// ---- pack: Wt[n][d] (split hi/lo) = W_z[h][d][e], n = z*1024 + h*64 + e ----
__global__ __launch_bounds__(256) void pack_w(const float* __restrict__ Wq,
                                              const float* __restrict__ Wk,
                                              const float* __restrict__ Wv,
                                              u16* __restrict__ Wth,
                                              u16* __restrict__ Wtl)
{
    __shared__ float Tl[64*68];
    const int h = blockIdx.x, dt = blockIdx.y, z = blockIdx.z;
    const float* src = (z==0) ? Wq : ((z==1) ? Wk : Wv);
    const int t = threadIdx.x;
    const int d0 = dt*64;
    #pragma unroll
    for (int i=0;i<4;++i){
        int ci = t + 256*i;
        int dr = ci>>4, ec = ci&15;
        float4 v = *(const float4*)(src + ((size_t)h*D_ + d0+dr)*HS_ + ec*4);
        *(float4*)(Tl + dr*68 + ec*4) = v;
    }
    __syncthreads();
    #pragma unroll
    for (int i=0;i<4;++i){
        int ci = t + 256*i;
        int e = ci>>4, dc = ci&15;
        U4 hh, ll;
        #pragma unroll
        for (int j=0;j<4;++j){
            float f = Tl[(dc*4+j)*68 + e];
            split2(f, hh.s[j], ll.s[j]);
        }
        int n = z*D_ + h*HS_ + e;
        *(uint2*)(Wth + (size_t)n*D_ + d0 + dc*4) = hh.v;
        *(uint2*)(Wtl + (size_t)n*D_ + d0 + dc*4) = ll.v;
    }
}

// ---- QKV GEMM: qkv[t][col] = x[t][:]·Wt[col][:], col in [0,3072) ----
// PS=true: A staged from pre-split xh/xl via GLD16 (pure async, zero VALU/ds_write
// in loop); q written pre-split. PS=false: round-4 path (bit-identical output).
template<bool PS>
__global__ __launch_bounds__(256) void gemm_qkv(const float* __restrict__ x,
                                                const u16* __restrict__ xh, const u16* __restrict__ xl,
                                                const u16* __restrict__ Wth,
                                                const u16* __restrict__ Wtl,
                                                float* __restrict__ qo,
                                                u16* __restrict__ qho, u16* __restrict__ qlo,
                                                u16* __restrict__ kho, u16* __restrict__ klo,
                                                u16* __restrict__ vth, u16* __restrict__ vtl)
{
    __shared__ u16 Ash[128*32], Asl[128*32];
    __shared__ u16 Bsh[128*32], Bsl[128*32];
    const int n0 = blockIdx.x*128, m0 = blockIdx.y*128;
    const int t = threadIdx.x;
    const int w = t>>6, lane = t&63, quad = lane>>4, l16 = lane&15;
    const int wm = (w>>1)*64, wn = (w&1)*64;
    f32x4 acc[4][4];
    #pragma unroll
    for (int i=0;i<4;++i)
        #pragma unroll
        for (int j=0;j<4;++j) acc[i][j] = (f32x4){0.f,0.f,0.f,0.f};
    for (int kt=0; kt<32; ++kt){
        const int k0 = kt*32;
        #pragma unroll
        for (int i=0;i<2;++i){           // B: async 16B chunks, pre-swizzled source
            int ci = t + 256*i;
            int row = ci>>2, c = ci&3;
            int cs = c ^ FCHK(row);
            GLD16(Wth + (size_t)(n0+row)*D_ + k0 + cs*8, Bsh + ci*8);
            GLD16(Wtl + (size_t)(n0+row)*D_ + k0 + cs*8, Bsl + ci*8);
        }
        if constexpr(PS){
            #pragma unroll
            for (int i=0;i<2;++i){       // A: async too (pre-split x)
                int ci = t + 256*i;
                int row = ci>>2, c = ci&3;
                int cs = c ^ FCHK(row);
                GLD16(xh + (size_t)(m0+row)*D_ + k0 + cs*8, Ash + ci*8);
                GLD16(xl + (size_t)(m0+row)*D_ + k0 + cs*8, Asl + ci*8);
            }
        } else {
            #pragma unroll
            for (int i=0;i<4;++i){       // A: f32 load + split, swizzled ds_write
                int ci = t + 256*i;
                int row = ci>>3, c4 = ci&7;
                float4 av = *(const float4*)(x + (size_t)(m0+row)*D_ + k0 + c4*4);
                U4 hh, ll;
                split2(av.x, hh.s[0], ll.s[0]); split2(av.y, hh.s[1], ll.s[1]);
                split2(av.z, hh.s[2], ll.s[2]); split2(av.w, hh.s[3], ll.s[3]);
                int off = row*32 + ((((c4>>1) ^ FCHK(row))<<3) | ((c4&1)<<2));
                *(uint2*)(Ash + off) = hh.v;
                *(uint2*)(Asl + off) = ll.v;
            }
        }
        __syncthreads();
        short8 afh[4], afl[4], bfh[4], bfl[4];
        #pragma unroll
        for (int mi=0;mi<4;++mi){
            const int rr = wm+mi*16+l16;
            const int off = rr*32 + ((quad ^ FCHK(rr))<<3);
            afh[mi] = *(const short8*)(Ash + off);
            afl[mi] = *(const short8*)(Asl + off);
        }
        #pragma unroll
        for (int ni=0;ni<4;++ni){
            const int rr = wn+ni*16+l16;
            const int off = rr*32 + ((quad ^ FCHK(rr))<<3);
            bfh[ni] = *(const short8*)(Bsh + off);
            bfl[ni] = *(const short8*)(Bsl + off);
        }
        #pragma unroll
        for (int mi=0;mi<4;++mi)
            #pragma unroll
            for (int ni=0;ni<4;++ni){
                acc[mi][ni] = __builtin_amdgcn_mfma_f32_16x16x32_bf16(afh[mi], bfh[ni], acc[mi][ni], 0,0,0);
                acc[mi][ni] = __builtin_amdgcn_mfma_f32_16x16x32_bf16(afh[mi], bfl[ni], acc[mi][ni], 0,0,0);
                acc[mi][ni] = __builtin_amdgcn_mfma_f32_16x16x32_bf16(afl[mi], bfh[ni], acc[mi][ni], 0,0,0);
            }
        __syncthreads();
    }
    const int z = n0 >> 10;              // block-uniform (128 | 1024)
    if (z <= 1){
        if constexpr(PS){
            u16* dh = z ? kho : qho;
            u16* dl = z ? klo : qlo;
            #pragma unroll
            for (int ni=0;ni<4;++ni){
                const int nloc = (n0 & 1023) + wn + ni*16 + l16;
                #pragma unroll
                for (int mi=0;mi<4;++mi){
                    const int row = m0 + wm + mi*16 + quad*4;
                    #pragma unroll
                    for (int r=0;r<4;++r){
                        u16 hh, ll; split2(acc[mi][ni][r], hh, ll);
                        dh[(size_t)(row+r)*D_ + nloc] = hh;
                        dl[(size_t)(row+r)*D_ + nloc] = ll;
                    }
                }
            }
        } else {
            if (z == 0){
                #pragma unroll
                for (int ni=0;ni<4;++ni){
                    const int nloc = (n0 & 1023) + wn + ni*16 + l16;
                    #pragma unroll
                    for (int mi=0;mi<4;++mi){
                        const int row = m0 + wm + mi*16 + quad*4;
                        #pragma unroll
                        for (int r=0;r<4;++r)
                            qo[(size_t)(row+r)*D_ + nloc] = acc[mi][ni][r];
                    }
                }
            } else {
                #pragma unroll
                for (int ni=0;ni<4;++ni){
                    const int nloc = (n0 & 1023) + wn + ni*16 + l16;
                    #pragma unroll
                    for (int mi=0;mi<4;++mi){
                        const int row = m0 + wm + mi*16 + quad*4;
                        #pragma unroll
                        for (int r=0;r<4;++r){
                            u16 hh, ll; split2(acc[mi][ni][r], hh, ll);
                            kho[(size_t)(row+r)*D_ + nloc] = hh;
                            klo[(size_t)(row+r)*D_ + nloc] = ll;
                        }
                    }
                }
            }
        }
    } else {
        #pragma unroll
        for (int ni=0;ni<4;++ni){
            const int nloc = (n0 & 1023) + wn + ni*16 + l16;
            const int hloc = nloc>>6, e = nloc&63;
            #pragma unroll
            for (int mi=0;mi<4;++mi){
                const int rowb = m0 + wm + mi*16 + quad*4;   // multiple of 4
                const int bidx = rowb >> 11, tloc = rowb & 2047;
                U4 hh, ll;
                #pragma unroll
                for (int r=0;r<4;++r) split2(acc[mi][ni][r], hh.s[r], ll.s[r]);
                const size_t adr = ((size_t)((bidx*16 + hloc)*64 + e))*T_ + tloc;
                *(uint2*)(vth + adr) = hh.v;
                *(uint2*)(vtl + adr) = ll.v;
            }
        }
    }
}

// ---- causal flash attention, ROUND-7 geometry: 4-wave blocks, 64-row q-tiles,
// paired for balance (block px does qi=31-px then qi=px -> 33 tile-units each),
// 1024 blocks, 40 KB LDS -> 4 blocks/CU (160 KB exactly), ALL resident.
// Rationale: r5/r6 counters show no pipe saturated (MFMA 22, VALU 40, HBM 6%)
// -> lockstep-serialization wall. Halving the barrier group (8->4 waves) and
// doubling independent groups/CU (2->4) lets latency chains overlap.
// P buffer back to phased [16][64]/wave (hi then lo; r0-proven) to fit 40 KB.
// Prefetch issue restored BETWEEN barriers (r6's after-barrier placement was
// -6%: 199->212 µs, reverted).
// XCD grouping: same-bh blocks share L%8=bx. launch_bounds(256,4): min-blocks/CU
// semantics (r1-proven) -> 16 waves/CU -> 128-VGPR cap, no spill at ~100 VGPR. ----
template<bool PS>
__global__ __launch_bounds__(256, 4) void attn(const float* __restrict__ qf,
                                            const u16* __restrict__ qh, const u16* __restrict__ ql,
                                            const u16* __restrict__ kh, const u16* __restrict__ kl,
                                            const u16* __restrict__ vth, const u16* __restrict__ vtl,
                                            float* __restrict__ att,
                                            u16* __restrict__ atth, u16* __restrict__ attl)
{
    __shared__ u16 Ksh[64*64], Ksl[64*64];   // [kv][e], swizzled (16 KB)
    __shared__ u16 Vsh[64*64], Vsl[64*64];   // [e][kv], swizzled (16 KB)
    __shared__ u16 Pb[4*16*64];              // per-wave [16][64], phased h/l (8 KB)
    const int bx = blockIdx.x, by = blockIdx.y;
    const int bh = ((by & 7) << 3) | bx;     // same-bh blocks share bx = L%8 (XCD)
    const int px = by >> 3;                  // pair index 0..15
    const int b = bh >> 4, h = bh & 15;
    const int t = threadIdx.x;
    const int w = t>>6, lane = t&63, quad = lane>>4, l16 = lane&15;

    u16* Pm = Pb + w*1024;

    // staging geometry: 256 threads = 64 rows x 4 chunk-slots, 2 uint4/thread/array
    const int srow = t>>2, sc = t&3;
    const int slo0 = swz(srow, sc*8);
    const int slo1 = swz(srow, sc*8 + 32);
    uint4 pkh0, pkh1, pkl0, pkl1, pvh0, pvh1, pvl0, pvl1;   // register prefetch
    {   // prime kv tile 0 (segment 0)
        const size_t gk = ((size_t)(b*T_ + srow))*D_ + h*64 + sc*8;
        pkh0 = *(const uint4*)(kh + gk);  pkh1 = *(const uint4*)(kh + gk + 32);
        pkl0 = *(const uint4*)(kl + gk);  pkl1 = *(const uint4*)(kl + gk + 32);
        const size_t gv = ((size_t)(bh*64 + srow))*T_ + sc*8;
        pvh0 = *(const uint4*)(vth + gv); pvh1 = *(const uint4*)(vth + gv + 32);
        pvl0 = *(const uint4*)(vtl + gv); pvl1 = *(const uint4*)(vtl + gv + 32);
    }

    #pragma unroll 1
    for (int seg=0; seg<2; ++seg){
        const int qi = seg ? px : (31 - px); // heavy segment first
        const int qrow = qi*64 + w*16;       // wave's absolute q base

        short8 qh_[2], ql_[2];
        if constexpr(PS){
            const size_t qb = ((size_t)(b*T_ + qrow + l16))*D_ + h*64;
            #pragma unroll
            for (int ks=0;ks<2;++ks){
                qh_[ks] = *(const short8*)(qh + qb + ks*32 + quad*8);
                ql_[ks] = *(const short8*)(ql + qb + ks*32 + quad*8);
            }
        } else {
            const float* qp = qf + ((size_t)(b*T_ + qrow + l16))*D_ + h*64;
            #pragma unroll
            for (int ks=0;ks<2;++ks){
                float4 a0 = *(const float4*)(qp + ks*32 + quad*8);
                float4 a1 = *(const float4*)(qp + ks*32 + quad*8 + 4);
                S8 hh, ll;
                split2(a0.x, hh.s[0], ll.s[0]); split2(a0.y, hh.s[1], ll.s[1]);
                split2(a0.z, hh.s[2], ll.s[2]); split2(a0.w, hh.s[3], ll.s[3]);
                split2(a1.x, hh.s[4], ll.s[4]); split2(a1.y, hh.s[5], ll.s[5]);
                split2(a1.z, hh.s[6], ll.s[6]); split2(a1.w, hh.s[7], ll.s[7]);
                qh_[ks] = hh.v; ql_[ks] = ll.v;
            }
        }
        f32x4 o[4];
        #pragma unroll
        for (int i=0;i<4;++i) o[i] = (f32x4){0.f,0.f,0.f,0.f};
        float m_i[4], l_i[4];
        #pragma unroll
        for (int r=0;r<4;++r){ m_i[r] = -INFINITY; l_i[r] = 0.f; }

        const int kvT = qi + 1;
        for (int kvt=0; kvt<kvT; ++kvt){
            __syncthreads();                 // prev-iter readers done
            *(uint4*)(Ksh + slo0) = pkh0;  *(uint4*)(Ksh + slo1) = pkh1;
            *(uint4*)(Ksl + slo0) = pkl0;  *(uint4*)(Ksl + slo1) = pkl1;
            *(uint4*)(Vsh + slo0) = pvh0;  *(uint4*)(Vsh + slo1) = pvh1;
            *(uint4*)(Vsl + slo0) = pvl0;  *(uint4*)(Vsl + slo1) = pvl1;
            // prefetch next tile (r5 placement: between barriers; r6 A/B-proven better)
            const int nk = (kvt+1 < kvT) ? (kvt+1) : ((seg==0) ? 0 : -1);
            if (nk >= 0){
                const size_t gk = ((size_t)(b*T_ + nk*64 + srow))*D_ + h*64 + sc*8;
                pkh0 = *(const uint4*)(kh + gk);  pkh1 = *(const uint4*)(kh + gk + 32);
                pkl0 = *(const uint4*)(kl + gk);  pkl1 = *(const uint4*)(kl + gk + 32);
                const size_t gv = ((size_t)(bh*64 + srow))*T_ + nk*64 + sc*8;
                pvh0 = *(const uint4*)(vth + gv); pvh1 = *(const uint4*)(vth + gv + 32);
                pvl0 = *(const uint4*)(vtl + gv); pvl1 = *(const uint4*)(vtl + gv + 32);
            }
            __syncthreads();

            float s[4][4];
            __builtin_amdgcn_s_setprio(1);
            #pragma unroll
            for (int ni=0;ni<4;++ni){
                f32x4 sa = (f32x4){0.f,0.f,0.f,0.f};
                const int row = ni*16 + l16;
                #pragma unroll
                for (int ks=0;ks<2;++ks){
                    const int co = swz(row, ks*32 + quad*8);
                    short8 k8h = *(const short8*)(Ksh + co);
                    short8 k8l = *(const short8*)(Ksl + co);
                    sa = __builtin_amdgcn_mfma_f32_16x16x32_bf16(qh_[ks], k8h, sa, 0,0,0);
                    sa = __builtin_amdgcn_mfma_f32_16x16x32_bf16(qh_[ks], k8l, sa, 0,0,0);
                    sa = __builtin_amdgcn_mfma_f32_16x16x32_bf16(ql_[ks], k8h, sa, 0,0,0);
                }
                #pragma unroll
                for (int r=0;r<4;++r) s[ni][r] = sa[r]*0.125f;
            }
            __builtin_amdgcn_s_setprio(0);
            // causal mask iff tile max col can exceed wave MIN row (diagonal tile)
            if (kvt*64 + 63 > qrow){
                #pragma unroll
                for (int ni=0;ni<4;++ni){
                    const int colabs = kvt*64 + ni*16 + l16;
                    #pragma unroll
                    for (int r=0;r<4;++r){
                        const int rowabs = qrow + quad*4 + r;
                        if (colabs > rowabs) s[ni][r] = -INFINITY;
                    }
                }
            }
            float alpha[4];
            #pragma unroll
            for (int r=0;r<4;++r){
                float rm = fmaxf(fmaxf(s[0][r],s[1][r]), fmaxf(s[2][r],s[3][r]));
                rm = fmaxf(rm, DPPMV(rm, 0xB1));   // quad_perm xor1
                rm = fmaxf(rm, DPPMV(rm, 0x4E));   // quad_perm xor2
                rm = fmaxf(rm, DPPMV(rm, 0x124));  // row_ror:4
                rm = fmaxf(rm, DPPMV(rm, 0x128));  // row_ror:8
                const float mnew = fmaxf(m_i[r], rm);
                alpha[r] = __expf(m_i[r] - mnew);
                m_i[r] = mnew;
                #pragma unroll
                for (int ni=0;ni<4;++ni) s[ni][r] = __expf(s[ni][r] - mnew);  // in place
                float rs = s[0][r]+s[1][r]+s[2][r]+s[3][r];
                rs += DPPMV(rs, 0xB1);
                rs += DPPMV(rs, 0x4E);
                rs += DPPMV(rs, 0x124);
                rs += DPPMV(rs, 0x128);
                l_i[r] = l_i[r]*alpha[r] + rs;
            }
            #pragma unroll
            for (int ni=0;ni<4;++ni)
                #pragma unroll
                for (int r=0;r<4;++r) o[ni][r] *= alpha[r];

            // ---- P: split once; phased h then l through per-wave [16][64] ----
            u16 ph[4][4], pl[4][4];
            #pragma unroll
            for (int ni=0;ni<4;++ni)
                #pragma unroll
                for (int r=0;r<4;++r)
                    split2(s[ni][r], ph[ni][r], pl[ni][r]);
            #pragma unroll
            for (int ni=0;ni<4;++ni)
                #pragma unroll
                for (int r=0;r<4;++r)
                    Pm[swz(quad*4+r, ni*16 + l16)] = ph[ni][r];
            __asm__ volatile("s_waitcnt lgkmcnt(0)" ::: "memory");
            short8 pah[2], pal[2];
            #pragma unroll
            for (int ks=0;ks<2;++ks)
                pah[ks] = *(const short8*)(Pm + swz(l16, ks*32 + quad*8));
            __asm__ volatile("" ::: "memory");   // keep reads before the l-overwrite
            #pragma unroll
            for (int ni=0;ni<4;++ni)
                #pragma unroll
                for (int r=0;r<4;++r)
                    Pm[swz(quad*4+r, ni*16 + l16)] = pl[ni][r];
            __asm__ volatile("s_waitcnt lgkmcnt(0)" ::: "memory");
            #pragma unroll
            for (int ks=0;ks<2;++ks)
                pal[ks] = *(const short8*)(Pm + swz(l16, ks*32 + quad*8));
            __asm__ volatile("" ::: "memory");   // keep reads before next-iter overwrite

            __builtin_amdgcn_s_setprio(1);
            #pragma unroll
            for (int ni=0;ni<4;++ni){
                const int row = ni*16 + l16;
                #pragma unroll
                for (int ks=0;ks<2;++ks){
                    const int co = swz(row, ks*32 + quad*8);
                    short8 v8h = *(const short8*)(Vsh + co);
                    short8 v8l = *(const short8*)(Vsl + co);
                    o[ni] = __builtin_amdgcn_mfma_f32_16x16x32_bf16(pah[ks], v8h, o[ni], 0,0,0);
                    o[ni] = __builtin_amdgcn_mfma_f32_16x16x32_bf16(pah[ks], v8l, o[ni], 0,0,0);
                    o[ni] = __builtin_amdgcn_mfma_f32_16x16x32_bf16(pal[ks], v8h, o[ni], 0,0,0);
                }
            }
            __builtin_amdgcn_s_setprio(0);
        }
        const size_t ob = (size_t)(b*T_ + qrow);
        #pragma unroll
        for (int ni=0;ni<4;++ni){
            const int col = h*64 + ni*16 + l16;
            #pragma unroll
            for (int r=0;r<4;++r){
                const float v = o[ni][r] / l_i[r];
                const size_t idx = (ob + quad*4 + r)*D_ + col;
                if constexpr(PS){
                    u16 hh, ll; split2(v, hh, ll);
                    atth[idx] = hh; attl[idx] = ll;
                } else {
                    att[idx] = v;
                }
            }
        }
    }
}

// ---- out-proj GEMM. PS=true: A=atth/attl, B=Wph/Wpl, all GLD16.
// PS=false: round-4 f32-staged path. ----
template<bool PS>
__global__ __launch_bounds__(256) void gemm_bt(const float* __restrict__ A,
                                               const u16* __restrict__ Ath, const u16* __restrict__ Atl,
                                               const float* __restrict__ Bt,
                                               const u16* __restrict__ Bth, const u16* __restrict__ Btl,
                                               float* __restrict__ C,
                                               const float* __restrict__ bias,
                                               int M, int N, int K)
{
    __shared__ u16 Ash[128*32], Asl[128*32];
    __shared__ u16 Bsh[128*32], Bsl[128*32];
    const int n0 = blockIdx.x*128, m0 = blockIdx.y*128;
    const int t = threadIdx.x;
    const int w = t>>6, lane = t&63, quad = lane>>4, l16 = lane&15;
    const int wm = (w>>1)*64, wn = (w&1)*64;
    f32x4 acc[4][4];
    #pragma unroll
    for (int i=0;i<4;++i)
        #pragma unroll
        for (int j=0;j<4;++j) acc[i][j] = (f32x4){0.f,0.f,0.f,0.f};
    const int kT = K >> 5;
    for (int kt=0; kt<kT; ++kt){
        const int k0 = kt*32;
        if constexpr(PS){
            #pragma unroll
            for (int i=0;i<2;++i){
                int ci = t + 256*i;
                int row = ci>>2, c = ci&3;
                int cs = c ^ FCHK(row);
                GLD16(Ath + (size_t)(m0+row)*K + k0 + cs*8, Ash + ci*8);
                GLD16(Atl + (size_t)(m0+row)*K + k0 + cs*8, Asl + ci*8);
                GLD16(Bth + (size_t)(n0+row)*K + k0 + cs*8, Bsh + ci*8);
                GLD16(Btl + (size_t)(n0+row)*K + k0 + cs*8, Bsl + ci*8);
            }
        } else {
            #pragma unroll
            for (int i=0;i<4;++i){
                int ci = t + 256*i;
                int row = ci>>3, c4 = ci&7;
                float4 av = *(const float4*)(A  + (size_t)(m0+row)*K + k0 + c4*4);
                float4 bv = *(const float4*)(Bt + (size_t)(n0+row)*K + k0 + c4*4);
                U4 ah, al, bh, bl;
                split2(av.x, ah.s[0], al.s[0]); split2(av.y, ah.s[1], al.s[1]);
                split2(av.z, ah.s[2], al.s[2]); split2(av.w, ah.s[3], al.s[3]);
                split2(bv.x, bh.s[0], bl.s[0]); split2(bv.y, bh.s[1], bl.s[1]);
                split2(bv.z, bh.s[2], bl.s[2]); split2(bv.w, bh.s[3], bl.s[3]);
                int off = row*32 + ((((c4>>1) ^ FCHK(row))<<3) | ((c4&1)<<2));
                *(uint2*)(Ash + off) = ah.v;
                *(uint2*)(Asl + off) = al.v;
                *(uint2*)(Bsh + off) = bh.v;
                *(uint2*)(Bsl + off) = bl.v;
            }
        }
        __syncthreads();
        short8 afh[4], afl[4], bfh[4], bfl[4];
        #pragma unroll
        for (int mi=0;mi<4;++mi){
            const int rr = wm+mi*16+l16;
            const int off = rr*32 + ((quad ^ FCHK(rr))<<3);
            afh[mi] = *(const short8*)(Ash + off);
            afl[mi] = *(const short8*)(Asl + off);
        }
        #pragma unroll
        for (int ni=0;ni<4;++ni){
            const int rr = wn+ni*16+l16;
            const int off = rr*32 + ((quad ^ FCHK(rr))<<3);
            bfh[ni] = *(const short8*)(Bsh + off);
            bfl[ni] = *(const short8*)(Bsl + off);
        }
        #pragma unroll
        for (int mi=0;mi<4;++mi)
            #pragma unroll
            for (int ni=0;ni<4;++ni){
                acc[mi][ni] = __builtin_amdgcn_mfma_f32_16x16x32_bf16(afh[mi], bfh[ni], acc[mi][ni], 0,0,0);
                acc[mi][ni] = __builtin_amdgcn_mfma_f32_16x16x32_bf16(afh[mi], bfl[ni], acc[mi][ni], 0,0,0);
                acc[mi][ni] = __builtin_amdgcn_mfma_f32_16x16x32_bf16(afl[mi], bfh[ni], acc[mi][ni], 0,0,0);
            }
        __syncthreads();
    }
    #pragma unroll
    for (int ni=0;ni<4;++ni){
        const int col = n0 + wn + ni*16 + l16;
        const float bv = bias ? bias[col] : 0.f;
        #pragma unroll
        for (int mi=0;mi<4;++mi){
            const int row = m0 + wm + mi*16 + quad*4;
            #pragma unroll
            for (int r=0;r<4;++r)
                C[(size_t)(row+r)*N + col] = acc[mi][ni][r] + bv;
        }
    }
}

extern "C" void kernel_launch(void* const* d_in, const int* in_sizes, int n_in,
                              void* d_out, int out_size, void* d_ws, size_t ws_size,
                              hipStream_t stream)
{
    const float* x  = (const float*)d_in[0];
    const float* Wq = (const float*)d_in[1];
    const float* Wk = (const float*)d_in[2];
    const float* Wv = (const float*)d_in[3];
    const float* Wp = (const float*)d_in[4];
    const float* bp = (const float*)d_in[5];
    float* out = (float*)d_out;

    const size_t NE = (size_t)BT*D_;                  // 8.39M elems
    const size_t NEED = (10*NE + 2*(size_t)D_*D_)*2;  // 171,966,464 B

    if (ws_size >= NEED){
        // pre-split layout (172 MB)
        u16* xh   = (u16*)d_ws;
        u16* xl   = xh + NE;
        u16* qh   = xl + NE;
        u16* ql   = qh + NE;
        u16* kh   = ql + NE;
        u16* kl   = kh + NE;
        u16* vth  = kl + NE;
        u16* vtl  = vth + NE;
        u16* atth = vtl + NE;                 // [BT][1024] split pair
        u16* attl = atth + NE;
        u16* Wph  = attl + NE;                // [1024][1024] split pair
        u16* Wpl  = Wph + (size_t)D_*D_;
        // Wt aliases atth region (12.6 MB <= 16.8 MB): dead before attn writes atth
        u16* Wth  = atth;
        u16* Wtl  = Wth + (size_t)3072*D_;

        split_f32<<<1024, 256, 0, stream>>>(x,  xh,  xl,  (int)(NE/8));
        split_f32<<<512,  256, 0, stream>>>(Wp, Wph, Wpl, (int)(((size_t)D_*D_)/8));
        pack_w   <<<dim3(16,16,3), 256, 0, stream>>>(Wq, Wk, Wv, Wth, Wtl);
        gemm_qkv<true><<<dim3(24, BT/128), 256, 0, stream>>>(x, xh, xl, Wth, Wtl,
                                                             nullptr, qh, ql, kh, kl, vth, vtl);
        attn<true><<<dim3(8, 128), 256, 0, stream>>>(nullptr, qh, ql, kh, kl, vth, vtl,
                                                     nullptr, atth, attl);
        gemm_bt<true><<<dim3(8, BT/128), 256, 0, stream>>>(nullptr, atth, attl,
                                                           nullptr, Wph, Wpl,
                                                           out, bp, BT, D_, D_);
    } else {
        // round-4 fallback layout (134.2 MB)
        float* q   = (float*)d_ws;
        u16*  kh   = (u16*)(q + NE);
        u16*  kl   = kh + NE;
        u16*  vth  = kl + NE;
        u16*  vtl  = vth + NE;
        float* att = (float*)(vtl + NE);
        u16*  Wth  = (u16*)att;
        u16*  Wtl  = Wth + (size_t)3072*D_;

        pack_w   <<<dim3(16,16,3), 256, 0, stream>>>(Wq, Wk, Wv, Wth, Wtl);
        gemm_qkv<false><<<dim3(24, BT/128), 256, 0, stream>>>(x, nullptr, nullptr, Wth, Wtl,
                                                              q, nullptr, nullptr, kh, kl, vth, vtl);
        attn<false><<<dim3(8, 128), 256, 0, stream>>>(q, nullptr, nullptr, kh, kl, vth, vtl,
                                                      att, nullptr, nullptr);
        gemm_bt<false><<<dim3(8, BT/128), 256, 0, stream>>>(att, nullptr, nullptr,
                                                            Wp, nullptr, nullptr,
                                                            out, bp, BT, D_, D_);
    }
}

// Round 8
// 501.462 us; speedup vs baseline: 1.3147x; 1.3147x over previous
//
#include <hip/hip_runtime.h>
#include <hip/hip_bf16.h>

typedef unsigned short u16;
typedef unsigned int u32;
typedef __attribute__((ext_vector_type(8))) short short8;
typedef __attribute__((ext_vector_type(4))) float f32x4;

#define B_ 4
#define T_ 2048
#define D_ 1024
#define H_ 16
#define HS_ 64
#define BT (B_*T_)

__device__ __forceinline__ float bf2f(u16 b){ union{u32 u; float f;} v; v.u=((u32)b)<<16; return v.f; }
__device__ __forceinline__ u16 f2bf(float f){
    __hip_bfloat16 h = __float2bfloat16(f);
    union{__hip_bfloat16 h; u16 u;} v; v.h = h; return v.u;
}
// split f32 into hi/lo bf16: x ~= hi + lo
__device__ __forceinline__ void split2(float x, u16& h, u16& l){
    u16 hb = f2bf(x);
    float fh = bf2f(hb);
    h = hb; l = f2bf(x - fh);
}
union U4 { u16 s[4]; uint2 v; };
union S8 { u16 s[8]; short8 v; };

// async global->LDS, 16B per lane; LDS dest wave-linear (base + lane*16)
#define GLD16(g,l) __builtin_amdgcn_global_load_lds( \
    (__attribute__((address_space(1))) void*)(u16*)(g), \
    (__attribute__((address_space(3))) void*)(l), 16, 0, 0)

// XOR-swizzled offset into a row-major [R][64]-u16 LDS tile, 16B-chunk granularity.
// Conflict-free with the t>>3 staging pattern (r5: SQ_LDS_BANK_CONFLICT == 0).
__device__ __forceinline__ int swz(int row, int col){
    return row*64 + (((col>>3) ^ (row&7))<<3) + (col&7);
}
// chunk-swizzle for the GEMM [128][32]-u16 tiles (64B rows, 4 x 16B chunks).
// Proven: SQ_LDS_BANK_CONFLICT 12.6M -> 0 (round 4).
#define FCHK(r) (((r)>>1)&3)

// DPP cross-lane move within a 16-lane row
#define DPPMV(x, ctrl) __int_as_float(__builtin_amdgcn_update_dpp(0, __float_as_int(x), (ctrl), 0xF, 0xF, true))

// ---- pack: Wt[n][d] (split hi/lo) = W_z[h][d][e], n = z*1024 + h*64 + e ----
__global__ __launch_bounds__(256) void pack_w(const float* __restrict__ Wq,
                                              const float* __restrict__ Wk,
                                              const float* __restrict__ Wv,
                                              u16* __restrict__ Wth,
                                              u16* __restrict__ Wtl)
{
    __shared__ float Tl[64*68];
    const int h = blockIdx.x, dt = blockIdx.y, z = blockIdx.z;
    const float* src = (z==0) ? Wq : ((z==1) ? Wk : Wv);
    const int t = threadIdx.x;
    const int d0 = dt*64;
    #pragma unroll
    for (int i=0;i<4;++i){
        int ci = t + 256*i;
        int dr = ci>>4, ec = ci&15;
        float4 v = *(const float4*)(src + ((size_t)h*D_ + d0+dr)*HS_ + ec*4);
        *(float4*)(Tl + dr*68 + ec*4) = v;
    }
    __syncthreads();
    #pragma unroll
    for (int i=0;i<4;++i){
        int ci = t + 256*i;
        int e = ci>>4, dc = ci&15;
        U4 hh, ll;
        #pragma unroll
        for (int j=0;j<4;++j){
            float f = Tl[(dc*4+j)*68 + e];
            split2(f, hh.s[j], ll.s[j]);
        }
        int n = z*D_ + h*HS_ + e;
        *(uint2*)(Wth + (size_t)n*D_ + d0 + dc*4) = hh.v;
        *(uint2*)(Wtl + (size_t)n*D_ + d0 + dc*4) = ll.v;
    }
}

// ---- QKV GEMM: qkv[t][col] = x[t][:]·Wt[col][:], col in [0,3072) ----
// LDS chunk-swizzled (FCHK): B via pre-swizzled GLOBAL source, A via swizzled ds_write.
__global__ __launch_bounds__(256) void gemm_qkv(const float* __restrict__ x,
                                                const u16* __restrict__ Wth,
                                                const u16* __restrict__ Wtl,
                                                float* __restrict__ qo,
                                                u16* __restrict__ kho, u16* __restrict__ klo,
                                                u16* __restrict__ vth, u16* __restrict__ vtl)
{
    __shared__ u16 Ash[128*32], Asl[128*32];
    __shared__ u16 Bsh[128*32], Bsl[128*32];
    const int n0 = blockIdx.x*128, m0 = blockIdx.y*128;
    const int t = threadIdx.x;
    const int w = t>>6, lane = t&63, quad = lane>>4, l16 = lane&15;
    const int wm = (w>>1)*64, wn = (w&1)*64;
    f32x4 acc[4][4];
    #pragma unroll
    for (int i=0;i<4;++i)
        #pragma unroll
        for (int j=0;j<4;++j) acc[i][j] = (f32x4){0.f,0.f,0.f,0.f};
    for (int kt=0; kt<32; ++kt){
        const int k0 = kt*32;
        #pragma unroll
        for (int i=0;i<2;++i){           // B: async 16B chunks, pre-swizzled source
            int ci = t + 256*i;
            int row = ci>>2, c = ci&3;
            int cs = c ^ FCHK(row);
            GLD16(Wth + (size_t)(n0+row)*D_ + k0 + cs*8, Bsh + ci*8);
            GLD16(Wtl + (size_t)(n0+row)*D_ + k0 + cs*8, Bsl + ci*8);
        }
        #pragma unroll
        for (int i=0;i<4;++i){           // A: f32 load + split, swizzled ds_write
            int ci = t + 256*i;
            int row = ci>>3, c4 = ci&7;
            float4 av = *(const float4*)(x + (size_t)(m0+row)*D_ + k0 + c4*4);
            U4 hh, ll;
            split2(av.x, hh.s[0], ll.s[0]); split2(av.y, hh.s[1], ll.s[1]);
            split2(av.z, hh.s[2], ll.s[2]); split2(av.w, hh.s[3], ll.s[3]);
            int off = row*32 + ((((c4>>1) ^ FCHK(row))<<3) | ((c4&1)<<2));
            *(uint2*)(Ash + off) = hh.v;
            *(uint2*)(Asl + off) = ll.v;
        }
        __syncthreads();
        short8 afh[4], afl[4], bfh[4], bfl[4];
        #pragma unroll
        for (int mi=0;mi<4;++mi){
            const int rr = wm+mi*16+l16;
            const int off = rr*32 + ((quad ^ FCHK(rr))<<3);
            afh[mi] = *(const short8*)(Ash + off);
            afl[mi] = *(const short8*)(Asl + off);
        }
        #pragma unroll
        for (int ni=0;ni<4;++ni){
            const int rr = wn+ni*16+l16;
            const int off = rr*32 + ((quad ^ FCHK(rr))<<3);
            bfh[ni] = *(const short8*)(Bsh + off);
            bfl[ni] = *(const short8*)(Bsl + off);
        }
        #pragma unroll
        for (int mi=0;mi<4;++mi)
            #pragma unroll
            for (int ni=0;ni<4;++ni){
                acc[mi][ni] = __builtin_amdgcn_mfma_f32_16x16x32_bf16(afh[mi], bfh[ni], acc[mi][ni], 0,0,0);
                acc[mi][ni] = __builtin_amdgcn_mfma_f32_16x16x32_bf16(afh[mi], bfl[ni], acc[mi][ni], 0,0,0);
                acc[mi][ni] = __builtin_amdgcn_mfma_f32_16x16x32_bf16(afl[mi], bfh[ni], acc[mi][ni], 0,0,0);
            }
        __syncthreads();
    }
    const int z = n0 >> 10;              // block-uniform (128 | 1024)
    if (z == 0){
        #pragma unroll
        for (int ni=0;ni<4;++ni){
            const int nloc = (n0 & 1023) + wn + ni*16 + l16;
            #pragma unroll
            for (int mi=0;mi<4;++mi){
                const int row = m0 + wm + mi*16 + quad*4;
                #pragma unroll
                for (int r=0;r<4;++r)
                    qo[(size_t)(row+r)*D_ + nloc] = acc[mi][ni][r];
            }
        }
    } else if (z == 1){
        #pragma unroll
        for (int ni=0;ni<4;++ni){
            const int nloc = (n0 & 1023) + wn + ni*16 + l16;
            #pragma unroll
            for (int mi=0;mi<4;++mi){
                const int row = m0 + wm + mi*16 + quad*4;
                #pragma unroll
                for (int r=0;r<4;++r){
                    u16 hh, ll; split2(acc[mi][ni][r], hh, ll);
                    kho[(size_t)(row+r)*D_ + nloc] = hh;
                    klo[(size_t)(row+r)*D_ + nloc] = ll;
                }
            }
        }
    } else {
        #pragma unroll
        for (int ni=0;ni<4;++ni){
            const int nloc = (n0 & 1023) + wn + ni*16 + l16;
            const int hloc = nloc>>6, e = nloc&63;
            #pragma unroll
            for (int mi=0;mi<4;++mi){
                const int rowb = m0 + wm + mi*16 + quad*4;   // multiple of 4
                const int bidx = rowb >> 11, tloc = rowb & 2047;
                U4 hh, ll;
                #pragma unroll
                for (int r=0;r<4;++r) split2(acc[mi][ni][r], hh.s[r], ll.s[r]);
                const size_t adr = ((size_t)((bidx*16 + hloc)*64 + e))*T_ + tloc;
                *(uint2*)(vth + adr) = hh.v;
                *(uint2*)(vtl + adr) = ll.v;
            }
        }
    }
}

// ---- causal flash attention, ROUND-8: clean de-lockstep retest.
// 4-wave blocks, 64-row q-tiles, paired for balance (block px: qi=31-px then px
// -> 33 tile-units each), grid (8,128), 40 KB LDS -> 4 blocks/CU (16 independent
// barrier groups vs r5's 2 -> latency chains overlap across groups).
// r7's two bugs fixed:
//  (1) __launch_bounds__(256, 2): collated evidence (512,4)->cap64, (512,2)->cap128,
//      (256,4)->cap64 ==> cap = 256/arg2 (NOT blocks/CU). arg2=2 -> 128-VGPR cap,
//      no spill at ~100 natural VGPR.
//  (2) staging uses r5's conflict-free addressing verbatim (ci=t+256*i, srow=ci>>3,
//      sc=ci&7), 2 chunks/thread, named prefetch regs (no dyn indexing).
// P buffer phased [16][64]/wave (hi then lo; r0-proven) to fit 40 KB.
// Prefetch issue between barriers (r6 A/B: after-barrier was -6%). ----
__global__ __launch_bounds__(256, 2) void attn(const float* __restrict__ qf,
                                            const u16* __restrict__ kh, const u16* __restrict__ kl,
                                            const u16* __restrict__ vth, const u16* __restrict__ vtl,
                                            float* __restrict__ att)
{
    __shared__ u16 Ksh[64*64], Ksl[64*64];   // [kv][e], swizzled (16 KB)
    __shared__ u16 Vsh[64*64], Vsl[64*64];   // [e][kv], swizzled (16 KB)
    __shared__ u16 Pb[4*16*64];              // per-wave [16][64], phased h/l (8 KB)
    const int bx = blockIdx.x, by = blockIdx.y;
    const int bh = ((by & 7) << 3) | bx;     // same-bh blocks share bx = L%8 (XCD)
    const int px = by >> 3;                  // pair index 0..15
    const int b = bh >> 4, h = bh & 15;
    const int t = threadIdx.x;
    const int w = t>>6, lane = t&63, quad = lane>>4, l16 = lane&15;

    u16* Pm = Pb + w*1024;

    // staging geometry (r5-proven pattern): ci = t + 256*i, srow = ci>>3, sc = ci&7
    const int srow0 = t>>3,        sc0 = t&7;
    const int srow1 = (t+256)>>3,  sc1 = t&7;       // (t+256)&7 == t&7
    const int slo0 = swz(srow0, sc0*8);
    const int slo1 = swz(srow1, sc1*8);
    uint4 pkh0, pkh1, pkl0, pkl1, pvh0, pvh1, pvl0, pvl1;
    {   // prime kv tile 0 (segment 0)
        const size_t gk0 = ((size_t)(b*T_ + srow0))*D_ + h*64 + sc0*8;
        const size_t gk1 = ((size_t)(b*T_ + srow1))*D_ + h*64 + sc1*8;
        pkh0 = *(const uint4*)(kh + gk0);  pkh1 = *(const uint4*)(kh + gk1);
        pkl0 = *(const uint4*)(kl + gk0);  pkl1 = *(const uint4*)(kl + gk1);
        const size_t gv0 = ((size_t)(bh*64 + srow0))*T_ + sc0*8;
        const size_t gv1 = ((size_t)(bh*64 + srow1))*T_ + sc1*8;
        pvh0 = *(const uint4*)(vth + gv0); pvh1 = *(const uint4*)(vth + gv1);
        pvl0 = *(const uint4*)(vtl + gv0); pvl1 = *(const uint4*)(vtl + gv1);
    }

    #pragma unroll 1
    for (int seg=0; seg<2; ++seg){
        const int qi = seg ? px : (31 - px); // heavy segment first
        const int qrow = qi*64 + w*16;       // wave's absolute q base

        short8 qh_[2], ql_[2];
        {
            const float* qp = qf + ((size_t)(b*T_ + qrow + l16))*D_ + h*64;
            #pragma unroll
            for (int ks=0;ks<2;++ks){
                float4 a0 = *(const float4*)(qp + ks*32 + quad*8);
                float4 a1 = *(const float4*)(qp + ks*32 + quad*8 + 4);
                S8 hh, ll;
                split2(a0.x, hh.s[0], ll.s[0]); split2(a0.y, hh.s[1], ll.s[1]);
                split2(a0.z, hh.s[2], ll.s[2]); split2(a0.w, hh.s[3], ll.s[3]);
                split2(a1.x, hh.s[4], ll.s[4]); split2(a1.y, hh.s[5], ll.s[5]);
                split2(a1.z, hh.s[6], ll.s[6]); split2(a1.w, hh.s[7], ll.s[7]);
                qh_[ks] = hh.v; ql_[ks] = ll.v;
            }
        }
        f32x4 o[4];
        #pragma unroll
        for (int i=0;i<4;++i) o[i] = (f32x4){0.f,0.f,0.f,0.f};
        float m_i[4], l_i[4];
        #pragma unroll
        for (int r=0;r<4;++r){ m_i[r] = -INFINITY; l_i[r] = 0.f; }

        const int kvT = qi + 1;
        for (int kvt=0; kvt<kvT; ++kvt){
            __syncthreads();                 // prev-iter readers done
            *(uint4*)(Ksh + slo0) = pkh0;  *(uint4*)(Ksh + slo1) = pkh1;
            *(uint4*)(Ksl + slo0) = pkl0;  *(uint4*)(Ksl + slo1) = pkl1;
            *(uint4*)(Vsh + slo0) = pvh0;  *(uint4*)(Vsh + slo1) = pvh1;
            *(uint4*)(Vsl + slo0) = pvl0;  *(uint4*)(Vsl + slo1) = pvl1;
            // prefetch next tile (between barriers — r6-proven placement)
            const int nk = (kvt+1 < kvT) ? (kvt+1) : ((seg==0) ? 0 : -1);
            if (nk >= 0){
                const size_t gk0 = ((size_t)(b*T_ + nk*64 + srow0))*D_ + h*64 + sc0*8;
                const size_t gk1 = ((size_t)(b*T_ + nk*64 + srow1))*D_ + h*64 + sc1*8;
                pkh0 = *(const uint4*)(kh + gk0);  pkh1 = *(const uint4*)(kh + gk1);
                pkl0 = *(const uint4*)(kl + gk0);  pkl1 = *(const uint4*)(kl + gk1);
                const size_t gv0 = ((size_t)(bh*64 + srow0))*T_ + nk*64 + sc0*8;
                const size_t gv1 = ((size_t)(bh*64 + srow1))*T_ + nk*64 + sc1*8;
                pvh0 = *(const uint4*)(vth + gv0); pvh1 = *(const uint4*)(vth + gv1);
                pvl0 = *(const uint4*)(vtl + gv0); pvl1 = *(const uint4*)(vtl + gv1);
            }
            __syncthreads();

            float s[4][4];
            __builtin_amdgcn_s_setprio(1);
            #pragma unroll
            for (int ni=0;ni<4;++ni){
                f32x4 sa = (f32x4){0.f,0.f,0.f,0.f};
                const int row = ni*16 + l16;
                #pragma unroll
                for (int ks=0;ks<2;++ks){
                    const int co = swz(row, ks*32 + quad*8);
                    short8 k8h = *(const short8*)(Ksh + co);
                    short8 k8l = *(const short8*)(Ksl + co);
                    sa = __builtin_amdgcn_mfma_f32_16x16x32_bf16(qh_[ks], k8h, sa, 0,0,0);
                    sa = __builtin_amdgcn_mfma_f32_16x16x32_bf16(qh_[ks], k8l, sa, 0,0,0);
                    sa = __builtin_amdgcn_mfma_f32_16x16x32_bf16(ql_[ks], k8h, sa, 0,0,0);
                }
                #pragma unroll
                for (int r=0;r<4;++r) s[ni][r] = sa[r]*0.125f;
            }
            __builtin_amdgcn_s_setprio(0);
            // causal mask: only the kvt==qi tile can cross the diagonal
            if (kvt*64 + 63 > qrow){
                #pragma unroll
                for (int ni=0;ni<4;++ni){
                    const int colabs = kvt*64 + ni*16 + l16;
                    #pragma unroll
                    for (int r=0;r<4;++r){
                        const int rowabs = qrow + quad*4 + r;
                        if (colabs > rowabs) s[ni][r] = -INFINITY;
                    }
                }
            }
            float alpha[4];
            #pragma unroll
            for (int r=0;r<4;++r){
                float rm = fmaxf(fmaxf(s[0][r],s[1][r]), fmaxf(s[2][r],s[3][r]));
                rm = fmaxf(rm, DPPMV(rm, 0xB1));   // quad_perm xor1
                rm = fmaxf(rm, DPPMV(rm, 0x4E));   // quad_perm xor2
                rm = fmaxf(rm, DPPMV(rm, 0x124));  // row_ror:4
                rm = fmaxf(rm, DPPMV(rm, 0x128));  // row_ror:8
                const float mnew = fmaxf(m_i[r], rm);
                alpha[r] = __expf(m_i[r] - mnew);
                m_i[r] = mnew;
                #pragma unroll
                for (int ni=0;ni<4;++ni) s[ni][r] = __expf(s[ni][r] - mnew);  // in place
                float rs = s[0][r]+s[1][r]+s[2][r]+s[3][r];
                rs += DPPMV(rs, 0xB1);
                rs += DPPMV(rs, 0x4E);
                rs += DPPMV(rs, 0x124);
                rs += DPPMV(rs, 0x128);
                l_i[r] = l_i[r]*alpha[r] + rs;
            }
            #pragma unroll
            for (int ni=0;ni<4;++ni)
                #pragma unroll
                for (int r=0;r<4;++r) o[ni][r] *= alpha[r];

            // ---- P: split once; phased h then l through per-wave [16][64] ----
            u16 ph[4][4], pl[4][4];
            #pragma unroll
            for (int ni=0;ni<4;++ni)
                #pragma unroll
                for (int r=0;r<4;++r)
                    split2(s[ni][r], ph[ni][r], pl[ni][r]);
            #pragma unroll
            for (int ni=0;ni<4;++ni)
                #pragma unroll
                for (int r=0;r<4;++r)
                    Pm[swz(quad*4+r, ni*16 + l16)] = ph[ni][r];
            __asm__ volatile("s_waitcnt lgkmcnt(0)" ::: "memory");
            short8 pah[2], pal[2];
            #pragma unroll
            for (int ks=0;ks<2;++ks)
                pah[ks] = *(const short8*)(Pm + swz(l16, ks*32 + quad*8));
            __asm__ volatile("" ::: "memory");   // keep reads before the l-overwrite
            #pragma unroll
            for (int ni=0;ni<4;++ni)
                #pragma unroll
                for (int r=0;r<4;++r)
                    Pm[swz(quad*4+r, ni*16 + l16)] = pl[ni][r];
            __asm__ volatile("s_waitcnt lgkmcnt(0)" ::: "memory");
            #pragma unroll
            for (int ks=0;ks<2;++ks)
                pal[ks] = *(const short8*)(Pm + swz(l16, ks*32 + quad*8));
            __asm__ volatile("" ::: "memory");   // keep reads before next-iter overwrite

            __builtin_amdgcn_s_setprio(1);
            #pragma unroll
            for (int ni=0;ni<4;++ni){
                const int row = ni*16 + l16;
                #pragma unroll
                for (int ks=0;ks<2;++ks){
                    const int co = swz(row, ks*32 + quad*8);
                    short8 v8h = *(const short8*)(Vsh + co);
                    short8 v8l = *(const short8*)(Vsl + co);
                    o[ni] = __builtin_amdgcn_mfma_f32_16x16x32_bf16(pah[ks], v8h, o[ni], 0,0,0);
                    o[ni] = __builtin_amdgcn_mfma_f32_16x16x32_bf16(pah[ks], v8l, o[ni], 0,0,0);
                    o[ni] = __builtin_amdgcn_mfma_f32_16x16x32_bf16(pal[ks], v8h, o[ni], 0,0,0);
                }
            }
            __builtin_amdgcn_s_setprio(0);
        }
        const size_t ob = (size_t)(b*T_ + qrow);
        #pragma unroll
        for (int ni=0;ni<4;++ni){
            const int col = h*64 + ni*16 + l16;
            #pragma unroll
            for (int r=0;r<4;++r)
                att[(ob + quad*4 + r)*D_ + col] = o[ni][r] / l_i[r];
        }
    }
}

// ---- f32-in GEMM (A f32, Bt f32 [N,K], bias) for out-proj; chunk-swizzled LDS ----
__global__ __launch_bounds__(256) void gemm_bt(const float* __restrict__ A,
                                               const float* __restrict__ Bt,
                                               float* __restrict__ C,
                                               const float* __restrict__ bias,
                                               int M, int N, int K)
{
    __shared__ u16 Ash[128*32], Asl[128*32];
    __shared__ u16 Bsh[128*32], Bsl[128*32];
    const int n0 = blockIdx.x*128, m0 = blockIdx.y*128;
    const int t = threadIdx.x;
    const int w = t>>6, lane = t&63, quad = lane>>4, l16 = lane&15;
    const int wm = (w>>1)*64, wn = (w&1)*64;
    f32x4 acc[4][4];
    #pragma unroll
    for (int i=0;i<4;++i)
        #pragma unroll
        for (int j=0;j<4;++j) acc[i][j] = (f32x4){0.f,0.f,0.f,0.f};
    const int kT = K >> 5;
    for (int kt=0; kt<kT; ++kt){
        const int k0 = kt*32;
        #pragma unroll
        for (int i=0;i<4;++i){
            int ci = t + 256*i;
            int row = ci>>3, c4 = ci&7;
            float4 av = *(const float4*)(A  + (size_t)(m0+row)*K + k0 + c4*4);
            float4 bv = *(const float4*)(Bt + (size_t)(n0+row)*K + k0 + c4*4);
            U4 ah, al, bh, bl;
            split2(av.x, ah.s[0], al.s[0]); split2(av.y, ah.s[1], al.s[1]);
            split2(av.z, ah.s[2], al.s[2]); split2(av.w, ah.s[3], al.s[3]);
            split2(bv.x, bh.s[0], bl.s[0]); split2(bv.y, bh.s[1], bl.s[1]);
            split2(bv.z, bh.s[2], bl.s[2]); split2(bv.w, bh.s[3], bl.s[3]);
            int off = row*32 + ((((c4>>1) ^ FCHK(row))<<3) | ((c4&1)<<2));
            *(uint2*)(Ash + off) = ah.v;
            *(uint2*)(Asl + off) = al.v;
            *(uint2*)(Bsh + off) = bh.v;
            *(uint2*)(Bsl + off) = bl.v;
        }
        __syncthreads();
        short8 afh[4], afl[4], bfh[4], bfl[4];
        #pragma unroll
        for (int mi=0;mi<4;++mi){
            const int rr = wm+mi*16+l16;
            const int off = rr*32 + ((quad ^ FCHK(rr))<<3);
            afh[mi] = *(const short8*)(Ash + off);
            afl[mi] = *(const short8*)(Asl + off);
        }
        #pragma unroll
        for (int ni=0;ni<4;++ni){
            const int rr = wn+ni*16+l16;
            const int off = rr*32 + ((quad ^ FCHK(rr))<<3);
            bfh[ni] = *(const short8*)(Bsh + off);
            bfl[ni] = *(const short8*)(Bsl + off);
        }
        #pragma unroll
        for (int mi=0;mi<4;++mi)
            #pragma unroll
            for (int ni=0;ni<4;++ni){
                acc[mi][ni] = __builtin_amdgcn_mfma_f32_16x16x32_bf16(afh[mi], bfh[ni], acc[mi][ni], 0,0,0);
                acc[mi][ni] = __builtin_amdgcn_mfma_f32_16x16x32_bf16(afh[mi], bfl[ni], acc[mi][ni], 0,0,0);
                acc[mi][ni] = __builtin_amdgcn_mfma_f32_16x16x32_bf16(afl[mi], bfh[ni], acc[mi][ni], 0,0,0);
            }
        __syncthreads();
    }
    #pragma unroll
    for (int ni=0;ni<4;++ni){
        const int col = n0 + wn + ni*16 + l16;
        const float bv = bias ? bias[col] : 0.f;
        #pragma unroll
        for (int mi=0;mi<4;++mi){
            const int row = m0 + wm + mi*16 + quad*4;
            #pragma unroll
            for (int r=0;r<4;++r)
                C[(size_t)(row+r)*N + col] = acc[mi][ni][r] + bv;
        }
    }
}

extern "C" void kernel_launch(void* const* d_in, const int* in_sizes, int n_in,
                              void* d_out, int out_size, void* d_ws, size_t ws_size,
                              hipStream_t stream)
{
    const float* x  = (const float*)d_in[0];
    const float* Wq = (const float*)d_in[1];
    const float* Wk = (const float*)d_in[2];
    const float* Wv = (const float*)d_in[3];
    const float* Wp = (const float*)d_in[4];
    const float* bp = (const float*)d_in[5];
    float* out = (float*)d_out;

    // workspace layout (134.2 MB, round-4 proven footprint)
    float* q   = (float*)d_ws;                 // [BT][1024] f32
    u16*  kh   = (u16*)(q + (size_t)BT*D_);    // [BT][1024] u16
    u16*  kl   = kh + (size_t)BT*D_;
    u16*  vth  = kl + (size_t)BT*D_;           // [64bh][64e][2048t] u16
    u16*  vtl  = vth + (size_t)BT*D_;
    float* att = (float*)(vtl + (size_t)BT*D_);// [BT][1024] f32
    // Wt (split) aliases the att region: dead before attn writes att
    u16*  Wth  = (u16*)att;                    // [3072][1024] u16 (6.3 MB)
    u16*  Wtl  = Wth + (size_t)3072*D_;

    pack_w  <<<dim3(16,16,3), 256, 0, stream>>>(Wq, Wk, Wv, Wth, Wtl);
    gemm_qkv<<<dim3(24, BT/128), 256, 0, stream>>>(x, Wth, Wtl, q, kh, kl, vth, vtl);
    attn    <<<dim3(8, 128), 256, 0, stream>>>(q, kh, kl, vth, vtl, att);
    gemm_bt <<<dim3(8, BT/128), 256, 0, stream>>>(att, Wp, out, bp, BT, D_, D_);
}

// Round 9
// 491.780 us; speedup vs baseline: 1.3406x; 1.0197x over previous
//
#include <hip/hip_runtime.h>
#include <hip/hip_bf16.h>

typedef unsigned short u16;
typedef unsigned int u32;
typedef __attribute__((ext_vector_type(8))) short short8;
typedef __attribute__((ext_vector_type(4))) float f32x4;

#define B_ 4
#define T_ 2048
#define D_ 1024
#define H_ 16
#define HS_ 64
#define BT (B_*T_)

__device__ __forceinline__ float bf2f(u16 b){ union{u32 u; float f;} v; v.u=((u32)b)<<16; return v.f; }
__device__ __forceinline__ u16 f2bf(float f){
    __hip_bfloat16 h = __float2bfloat16(f);
    union{__hip_bfloat16 h; u16 u;} v; v.h = h; return v.u;
}
// split f32 into hi/lo bf16: x ~= hi + lo
__device__ __forceinline__ void split2(float x, u16& h, u16& l){
    u16 hb = f2bf(x);
    float fh = bf2f(hb);
    h = hb; l = f2bf(x - fh);
}
union U4 { u16 s[4]; uint2 v; };
union S8 { u16 s[8]; short8 v; };

// async global->LDS, 16B per lane; LDS dest wave-linear (base + lane*16)
#define GLD16(g,l) __builtin_amdgcn_global_load_lds( \
    (__attribute__((address_space(1))) void*)(u16*)(g), \
    (__attribute__((address_space(3))) void*)(l), 16, 0, 0)

// XOR-swizzled offset into a row-major [R][64]-u16 LDS tile, 16B-chunk granularity.
// Conflict-free with the t>>3 staging pattern (r5: SQ_LDS_BANK_CONFLICT == 0).
__device__ __forceinline__ int swz(int row, int col){
    return row*64 + (((col>>3) ^ (row&7))<<3) + (col&7);
}
// chunk-swizzle for the GEMM [128][32]-u16 tiles (64B rows, 4 x 16B chunks).
// Proven: SQ_LDS_BANK_CONFLICT 12.6M -> 0 (round 4).
#define FCHK(r) (((r)>>1)&3)

// ---- pack: Wt[n][d] (split hi/lo) = W_z[h][d][e], n = z*1024 + h*64 + e ----
__global__ __launch_bounds__(256) void pack_w(const float* __restrict__ Wq,
                                              const float* __restrict__ Wk,
                                              const float* __restrict__ Wv,
                                              u16* __restrict__ Wth,
                                              u16* __restrict__ Wtl)
{
    __shared__ float Tl[64*68];
    const int h = blockIdx.x, dt = blockIdx.y, z = blockIdx.z;
    const float* src = (z==0) ? Wq : ((z==1) ? Wk : Wv);
    const int t = threadIdx.x;
    const int d0 = dt*64;
    #pragma unroll
    for (int i=0;i<4;++i){
        int ci = t + 256*i;
        int dr = ci>>4, ec = ci&15;
        float4 v = *(const float4*)(src + ((size_t)h*D_ + d0+dr)*HS_ + ec*4);
        *(float4*)(Tl + dr*68 + ec*4) = v;
    }
    __syncthreads();
    #pragma unroll
    for (int i=0;i<4;++i){
        int ci = t + 256*i;
        int e = ci>>4, dc = ci&15;
        U4 hh, ll;
        #pragma unroll
        for (int j=0;j<4;++j){
            float f = Tl[(dc*4+j)*68 + e];
            split2(f, hh.s[j], ll.s[j]);
        }
        int n = z*D_ + h*HS_ + e;
        *(uint2*)(Wth + (size_t)n*D_ + d0 + dc*4) = hh.v;
        *(uint2*)(Wtl + (size_t)n*D_ + d0 + dc*4) = ll.v;
    }
}

// ---- QKV GEMM: qkv[t][col] = x[t][:]·Wt[col][:], col in [0,3072) ----
// LDS chunk-swizzled (FCHK): B via pre-swizzled GLOBAL source, A via swizzled ds_write.
__global__ __launch_bounds__(256) void gemm_qkv(const float* __restrict__ x,
                                                const u16* __restrict__ Wth,
                                                const u16* __restrict__ Wtl,
                                                float* __restrict__ qo,
                                                u16* __restrict__ kho, u16* __restrict__ klo,
                                                u16* __restrict__ vth, u16* __restrict__ vtl)
{
    __shared__ u16 Ash[128*32], Asl[128*32];
    __shared__ u16 Bsh[128*32], Bsl[128*32];
    const int n0 = blockIdx.x*128, m0 = blockIdx.y*128;
    const int t = threadIdx.x;
    const int w = t>>6, lane = t&63, quad = lane>>4, l16 = lane&15;
    const int wm = (w>>1)*64, wn = (w&1)*64;
    f32x4 acc[4][4];
    #pragma unroll
    for (int i=0;i<4;++i)
        #pragma unroll
        for (int j=0;j<4;++j) acc[i][j] = (f32x4){0.f,0.f,0.f,0.f};
    for (int kt=0; kt<32; ++kt){
        const int k0 = kt*32;
        #pragma unroll
        for (int i=0;i<2;++i){           // B: async 16B chunks, pre-swizzled source
            int ci = t + 256*i;
            int row = ci>>2, c = ci&3;
            int cs = c ^ FCHK(row);
            GLD16(Wth + (size_t)(n0+row)*D_ + k0 + cs*8, Bsh + ci*8);
            GLD16(Wtl + (size_t)(n0+row)*D_ + k0 + cs*8, Bsl + ci*8);
        }
        #pragma unroll
        for (int i=0;i<4;++i){           // A: f32 load + split, swizzled ds_write
            int ci = t + 256*i;
            int row = ci>>3, c4 = ci&7;
            float4 av = *(const float4*)(x + (size_t)(m0+row)*D_ + k0 + c4*4);
            U4 hh, ll;
            split2(av.x, hh.s[0], ll.s[0]); split2(av.y, hh.s[1], ll.s[1]);
            split2(av.z, hh.s[2], ll.s[2]); split2(av.w, hh.s[3], ll.s[3]);
            int off = row*32 + ((((c4>>1) ^ FCHK(row))<<3) | ((c4&1)<<2));
            *(uint2*)(Ash + off) = hh.v;
            *(uint2*)(Asl + off) = ll.v;
        }
        __syncthreads();
        short8 afh[4], afl[4], bfh[4], bfl[4];
        #pragma unroll
        for (int mi=0;mi<4;++mi){
            const int rr = wm+mi*16+l16;
            const int off = rr*32 + ((quad ^ FCHK(rr))<<3);
            afh[mi] = *(const short8*)(Ash + off);
            afl[mi] = *(const short8*)(Asl + off);
        }
        #pragma unroll
        for (int ni=0;ni<4;++ni){
            const int rr = wn+ni*16+l16;
            const int off = rr*32 + ((quad ^ FCHK(rr))<<3);
            bfh[ni] = *(const short8*)(Bsh + off);
            bfl[ni] = *(const short8*)(Bsl + off);
        }
        #pragma unroll
        for (int mi=0;mi<4;++mi)
            #pragma unroll
            for (int ni=0;ni<4;++ni){
                acc[mi][ni] = __builtin_amdgcn_mfma_f32_16x16x32_bf16(afh[mi], bfh[ni], acc[mi][ni], 0,0,0);
                acc[mi][ni] = __builtin_amdgcn_mfma_f32_16x16x32_bf16(afh[mi], bfl[ni], acc[mi][ni], 0,0,0);
                acc[mi][ni] = __builtin_amdgcn_mfma_f32_16x16x32_bf16(afl[mi], bfh[ni], acc[mi][ni], 0,0,0);
            }
        __syncthreads();
    }
    const int z = n0 >> 10;              // block-uniform (128 | 1024)
    if (z == 0){
        #pragma unroll
        for (int ni=0;ni<4;++ni){
            const int nloc = (n0 & 1023) + wn + ni*16 + l16;
            #pragma unroll
            for (int mi=0;mi<4;++mi){
                const int row = m0 + wm + mi*16 + quad*4;
                #pragma unroll
                for (int r=0;r<4;++r)
                    qo[(size_t)(row+r)*D_ + nloc] = acc[mi][ni][r];
            }
        }
    } else if (z == 1){
        #pragma unroll
        for (int ni=0;ni<4;++ni){
            const int nloc = (n0 & 1023) + wn + ni*16 + l16;
            #pragma unroll
            for (int mi=0;mi<4;++mi){
                const int row = m0 + wm + mi*16 + quad*4;
                #pragma unroll
                for (int r=0;r<4;++r){
                    u16 hh, ll; split2(acc[mi][ni][r], hh, ll);
                    kho[(size_t)(row+r)*D_ + nloc] = hh;
                    klo[(size_t)(row+r)*D_ + nloc] = ll;
                }
            }
        }
    } else {
        #pragma unroll
        for (int ni=0;ni<4;++ni){
            const int nloc = (n0 & 1023) + wn + ni*16 + l16;
            const int hloc = nloc>>6, e = nloc&63;
            #pragma unroll
            for (int mi=0;mi<4;++mi){
                const int rowb = m0 + wm + mi*16 + quad*4;   // multiple of 4
                const int bidx = rowb >> 11, tloc = rowb & 2047;
                U4 hh, ll;
                #pragma unroll
                for (int r=0;r<4;++r) split2(acc[mi][ni][r], hh.s[r], ll.s[r]);
                const size_t adr = ((size_t)((bidx*16 + hloc)*64 + e))*T_ + tloc;
                *(uint2*)(vth + adr) = hh.v;
                *(uint2*)(vtl + adr) = ll.v;
            }
        }
    }
}

// ---- causal flash attention, ROUND-9: SWAPPED QK^T (mfma(K,Q)) so each lane
// owns ONE q-row (q = l16) x 16 kv values. Same K LDS reads, same Q registers
// (operand order only). Gains vs r8:
//  * softmax: 15 in-reg fmax + 2 shfl_xor (was 16 DPP ops); alpha/m/l scalars.
//  * P store: 4 kv per (ni) are CONSECUTIVE -> 4x ds_write_b64 per phase
//    (was 16 scalar ds_write_u16) — attn is LDS-pipe-bound (r8 analysis:
//    ~2300 of ~3500 cyc/tile is LDS ops), write-op count is the lever.
//  * mask/epilogue reindexed: kv = ni*16+quad*4+r, q = qrow+l16.
// Shell unchanged from r8: 4-wave blocks, paired q-tiles, grid (8,128),
// 40 KB LDS, launch_bounds(256,2) [cap=256/arg2 model], staging r5 pattern,
// prefetch between barriers. ----
__global__ __launch_bounds__(256, 2) void attn(const float* __restrict__ qf,
                                            const u16* __restrict__ kh, const u16* __restrict__ kl,
                                            const u16* __restrict__ vth, const u16* __restrict__ vtl,
                                            float* __restrict__ att)
{
    __shared__ u16 Ksh[64*64], Ksl[64*64];   // [kv][e], swizzled (16 KB)
    __shared__ u16 Vsh[64*64], Vsl[64*64];   // [e][kv], swizzled (16 KB)
    __shared__ u16 Pb[4*16*64];              // per-wave [16][64], phased h/l (8 KB)
    const int bx = blockIdx.x, by = blockIdx.y;
    const int bh = ((by & 7) << 3) | bx;     // same-bh blocks share bx = L%8 (XCD)
    const int px = by >> 3;                  // pair index 0..15
    const int b = bh >> 4, h = bh & 15;
    const int t = threadIdx.x;
    const int w = t>>6, lane = t&63, quad = lane>>4, l16 = lane&15;

    u16* Pm = Pb + w*1024;

    // staging geometry (r5-proven pattern): ci = t + 256*i, srow = ci>>3, sc = ci&7
    const int srow0 = t>>3,        sc0 = t&7;
    const int srow1 = (t+256)>>3,  sc1 = t&7;       // (t+256)&7 == t&7
    const int slo0 = swz(srow0, sc0*8);
    const int slo1 = swz(srow1, sc1*8);
    uint4 pkh0, pkh1, pkl0, pkl1, pvh0, pvh1, pvl0, pvl1;
    {   // prime kv tile 0 (segment 0)
        const size_t gk0 = ((size_t)(b*T_ + srow0))*D_ + h*64 + sc0*8;
        const size_t gk1 = ((size_t)(b*T_ + srow1))*D_ + h*64 + sc1*8;
        pkh0 = *(const uint4*)(kh + gk0);  pkh1 = *(const uint4*)(kh + gk1);
        pkl0 = *(const uint4*)(kl + gk0);  pkl1 = *(const uint4*)(kl + gk1);
        const size_t gv0 = ((size_t)(bh*64 + srow0))*T_ + sc0*8;
        const size_t gv1 = ((size_t)(bh*64 + srow1))*T_ + sc1*8;
        pvh0 = *(const uint4*)(vth + gv0); pvh1 = *(const uint4*)(vth + gv1);
        pvl0 = *(const uint4*)(vtl + gv0); pvl1 = *(const uint4*)(vtl + gv1);
    }

    #pragma unroll 1
    for (int seg=0; seg<2; ++seg){
        const int qi = seg ? px : (31 - px); // heavy segment first
        const int qrow = qi*64 + w*16;       // wave's absolute q base
        const int q_abs = qrow + l16;        // this lane's q row (swapped layout)

        short8 qh_[2], ql_[2];
        {
            const float* qp = qf + ((size_t)(b*T_ + qrow + l16))*D_ + h*64;
            #pragma unroll
            for (int ks=0;ks<2;++ks){
                float4 a0 = *(const float4*)(qp + ks*32 + quad*8);
                float4 a1 = *(const float4*)(qp + ks*32 + quad*8 + 4);
                S8 hh, ll;
                split2(a0.x, hh.s[0], ll.s[0]); split2(a0.y, hh.s[1], ll.s[1]);
                split2(a0.z, hh.s[2], ll.s[2]); split2(a0.w, hh.s[3], ll.s[3]);
                split2(a1.x, hh.s[4], ll.s[4]); split2(a1.y, hh.s[5], ll.s[5]);
                split2(a1.z, hh.s[6], ll.s[6]); split2(a1.w, hh.s[7], ll.s[7]);
                qh_[ks] = hh.v; ql_[ks] = ll.v;
            }
        }
        f32x4 o[4];
        #pragma unroll
        for (int i=0;i<4;++i) o[i] = (f32x4){0.f,0.f,0.f,0.f};
        float m_i = -INFINITY, l_i = 0.f;    // scalar state: one q per lane

        const int kvT = qi + 1;
        for (int kvt=0; kvt<kvT; ++kvt){
            __syncthreads();                 // prev-iter readers done
            *(uint4*)(Ksh + slo0) = pkh0;  *(uint4*)(Ksh + slo1) = pkh1;
            *(uint4*)(Ksl + slo0) = pkl0;  *(uint4*)(Ksl + slo1) = pkl1;
            *(uint4*)(Vsh + slo0) = pvh0;  *(uint4*)(Vsh + slo1) = pvh1;
            *(uint4*)(Vsl + slo0) = pvl0;  *(uint4*)(Vsl + slo1) = pvl1;
            // prefetch next tile (between barriers — r6-proven placement)
            const int nk = (kvt+1 < kvT) ? (kvt+1) : ((seg==0) ? 0 : -1);
            if (nk >= 0){
                const size_t gk0 = ((size_t)(b*T_ + nk*64 + srow0))*D_ + h*64 + sc0*8;
                const size_t gk1 = ((size_t)(b*T_ + nk*64 + srow1))*D_ + h*64 + sc1*8;
                pkh0 = *(const uint4*)(kh + gk0);  pkh1 = *(const uint4*)(kh + gk1);
                pkl0 = *(const uint4*)(kl + gk0);  pkl1 = *(const uint4*)(kl + gk1);
                const size_t gv0 = ((size_t)(bh*64 + srow0))*T_ + nk*64 + sc0*8;
                const size_t gv1 = ((size_t)(bh*64 + srow1))*T_ + nk*64 + sc1*8;
                pvh0 = *(const uint4*)(vth + gv0); pvh1 = *(const uint4*)(vth + gv1);
                pvl0 = *(const uint4*)(vtl + gv0); pvl1 = *(const uint4*)(vtl + gv1);
            }
            __syncthreads();

            // ---- QK^T, SWAPPED: mfma(A=K, B=Q). C[m=kv][n=q]: lane holds
            // q = l16 (col), kv = ni*16 + quad*4 + r (row). Same Ksh reads,
            // same q registers as before — only operand order changed. ----
            float s[4][4];
            __builtin_amdgcn_s_setprio(1);
            #pragma unroll
            for (int ni=0;ni<4;++ni){
                f32x4 sa = (f32x4){0.f,0.f,0.f,0.f};
                const int row = ni*16 + l16;
                #pragma unroll
                for (int ks=0;ks<2;++ks){
                    const int co = swz(row, ks*32 + quad*8);
                    short8 k8h = *(const short8*)(Ksh + co);
                    short8 k8l = *(const short8*)(Ksl + co);
                    sa = __builtin_amdgcn_mfma_f32_16x16x32_bf16(k8h, qh_[ks], sa, 0,0,0);
                    sa = __builtin_amdgcn_mfma_f32_16x16x32_bf16(k8l, qh_[ks], sa, 0,0,0);
                    sa = __builtin_amdgcn_mfma_f32_16x16x32_bf16(k8h, ql_[ks], sa, 0,0,0);
                }
                #pragma unroll
                for (int r=0;r<4;++r) s[ni][r] = sa[r]*0.125f;
            }
            __builtin_amdgcn_s_setprio(0);
            // causal mask: kv > q  (kv = kvt*64 + ni*16 + quad*4 + r, q = q_abs)
            if (kvt*64 + 63 > qrow){
                #pragma unroll
                for (int ni=0;ni<4;++ni){
                    #pragma unroll
                    for (int r=0;r<4;++r){
                        const int kv_abs = kvt*64 + ni*16 + quad*4 + r;
                        if (kv_abs > q_abs) s[ni][r] = -INFINITY;
                    }
                }
            }
            // ---- online softmax, lane-local row + 2-step cross-quad reduce ----
            float rm = s[0][0];
            #pragma unroll
            for (int ni=0;ni<4;++ni)
                #pragma unroll
                for (int r=0;r<4;++r) rm = fmaxf(rm, s[ni][r]);
            rm = fmaxf(rm, __shfl_xor(rm, 16));
            rm = fmaxf(rm, __shfl_xor(rm, 32));
            const float mnew = fmaxf(m_i, rm);
            const float alpha = __expf(m_i - mnew);
            m_i = mnew;
            float rs = 0.f;
            #pragma unroll
            for (int ni=0;ni<4;++ni)
                #pragma unroll
                for (int r=0;r<4;++r){
                    s[ni][r] = __expf(s[ni][r] - mnew);
                    rs += s[ni][r];
                }
            rs += __shfl_xor(rs, 16);
            rs += __shfl_xor(rs, 32);
            l_i = l_i*alpha + rs;
            // broadcast alpha for the o-rescale (o rows are q = quad*4+r)
            float a4[4];
            #pragma unroll
            for (int r=0;r<4;++r) a4[r] = __shfl(alpha, quad*4 + r);
            #pragma unroll
            for (int ni=0;ni<4;++ni)
                #pragma unroll
                for (int r=0;r<4;++r) o[ni][r] *= a4[r];

            // ---- P: split once; phased h then l; b64 writes (4 consecutive kv) ----
            uint2 plv[4];
            #pragma unroll
            for (int ni=0;ni<4;++ni){
                U4 hh, ll;
                #pragma unroll
                for (int r=0;r<4;++r) split2(s[ni][r], hh.s[r], ll.s[r]);
                *(uint2*)(Pm + swz(l16, ni*16 + quad*4)) = hh.v;
                plv[ni] = ll.v;
            }
            __asm__ volatile("s_waitcnt lgkmcnt(0)" ::: "memory");
            short8 pah[2], pal[2];
            #pragma unroll
            for (int ks=0;ks<2;++ks)
                pah[ks] = *(const short8*)(Pm + swz(l16, ks*32 + quad*8));
            __asm__ volatile("" ::: "memory");   // keep reads before the l-overwrite
            #pragma unroll
            for (int ni=0;ni<4;++ni)
                *(uint2*)(Pm + swz(l16, ni*16 + quad*4)) = plv[ni];
            __asm__ volatile("s_waitcnt lgkmcnt(0)" ::: "memory");
            #pragma unroll
            for (int ks=0;ks<2;++ks)
                pal[ks] = *(const short8*)(Pm + swz(l16, ks*32 + quad*8));
            __asm__ volatile("" ::: "memory");   // keep reads before next-iter overwrite

            __builtin_amdgcn_s_setprio(1);
            #pragma unroll
            for (int ni=0;ni<4;++ni){
                const int row = ni*16 + l16;
                #pragma unroll
                for (int ks=0;ks<2;++ks){
                    const int co = swz(row, ks*32 + quad*8);
                    short8 v8h = *(const short8*)(Vsh + co);
                    short8 v8l = *(const short8*)(Vsl + co);
                    o[ni] = __builtin_amdgcn_mfma_f32_16x16x32_bf16(pah[ks], v8h, o[ni], 0,0,0);
                    o[ni] = __builtin_amdgcn_mfma_f32_16x16x32_bf16(pah[ks], v8l, o[ni], 0,0,0);
                    o[ni] = __builtin_amdgcn_mfma_f32_16x16x32_bf16(pal[ks], v8h, o[ni], 0,0,0);
                }
            }
            __builtin_amdgcn_s_setprio(0);
        }
        // epilogue: o rows are q = quad*4+r; l_i lives at lane q (quad-0 row)
        float lt[4];
        #pragma unroll
        for (int r=0;r<4;++r) lt[r] = __shfl(l_i, quad*4 + r);
        const size_t ob = (size_t)(b*T_ + qrow);
        #pragma unroll
        for (int ni=0;ni<4;++ni){
            const int col = h*64 + ni*16 + l16;
            #pragma unroll
            for (int r=0;r<4;++r)
                att[(ob + quad*4 + r)*D_ + col] = o[ni][r] / lt[r];
        }
    }
}

// ---- f32-in GEMM (A f32, Bt f32 [N,K], bias) for out-proj; chunk-swizzled LDS ----
__global__ __launch_bounds__(256) void gemm_bt(const float* __restrict__ A,
                                               const float* __restrict__ Bt,
                                               float* __restrict__ C,
                                               const float* __restrict__ bias,
                                               int M, int N, int K)
{
    __shared__ u16 Ash[128*32], Asl[128*32];
    __shared__ u16 Bsh[128*32], Bsl[128*32];
    const int n0 = blockIdx.x*128, m0 = blockIdx.y*128;
    const int t = threadIdx.x;
    const int w = t>>6, lane = t&63, quad = lane>>4, l16 = lane&15;
    const int wm = (w>>1)*64, wn = (w&1)*64;
    f32x4 acc[4][4];
    #pragma unroll
    for (int i=0;i<4;++i)
        #pragma unroll
        for (int j=0;j<4;++j) acc[i][j] = (f32x4){0.f,0.f,0.f,0.f};
    const int kT = K >> 5;
    for (int kt=0; kt<kT; ++kt){
        const int k0 = kt*32;
        #pragma unroll
        for (int i=0;i<4;++i){
            int ci = t + 256*i;
            int row = ci>>3, c4 = ci&7;
            float4 av = *(const float4*)(A  + (size_t)(m0+row)*K + k0 + c4*4);
            float4 bv = *(const float4*)(Bt + (size_t)(n0+row)*K + k0 + c4*4);
            U4 ah, al, bh, bl;
            split2(av.x, ah.s[0], al.s[0]); split2(av.y, ah.s[1], al.s[1]);
            split2(av.z, ah.s[2], al.s[2]); split2(av.w, ah.s[3], al.s[3]);
            split2(bv.x, bh.s[0], bl.s[0]); split2(bv.y, bh.s[1], bl.s[1]);
            split2(bv.z, bh.s[2], bl.s[2]); split2(bv.w, bh.s[3], bl.s[3]);
            int off = row*32 + ((((c4>>1) ^ FCHK(row))<<3) | ((c4&1)<<2));
            *(uint2*)(Ash + off) = ah.v;
            *(uint2*)(Asl + off) = al.v;
            *(uint2*)(Bsh + off) = bh.v;
            *(uint2*)(Bsl + off) = bl.v;
        }
        __syncthreads();
        short8 afh[4], afl[4], bfh[4], bfl[4];
        #pragma unroll
        for (int mi=0;mi<4;++mi){
            const int rr = wm+mi*16+l16;
            const int off = rr*32 + ((quad ^ FCHK(rr))<<3);
            afh[mi] = *(const short8*)(Ash + off);
            afl[mi] = *(const short8*)(Asl + off);
        }
        #pragma unroll
        for (int ni=0;ni<4;++ni){
            const int rr = wn+ni*16+l16;
            const int off = rr*32 + ((quad ^ FCHK(rr))<<3);
            bfh[ni] = *(const short8*)(Bsh + off);
            bfl[ni] = *(const short8*)(Bsl + off);
        }
        #pragma unroll
        for (int mi=0;mi<4;++mi)
            #pragma unroll
            for (int ni=0;ni<4;++ni){
                acc[mi][ni] = __builtin_amdgcn_mfma_f32_16x16x32_bf16(afh[mi], bfh[ni], acc[mi][ni], 0,0,0);
                acc[mi][ni] = __builtin_amdgcn_mfma_f32_16x16x32_bf16(afh[mi], bfl[ni], acc[mi][ni], 0,0,0);
                acc[mi][ni] = __builtin_amdgcn_mfma_f32_16x16x32_bf16(afl[mi], bfh[ni], acc[mi][ni], 0,0,0);
            }
        __syncthreads();
    }
    #pragma unroll
    for (int ni=0;ni<4;++ni){
        const int col = n0 + wn + ni*16 + l16;
        const float bv = bias ? bias[col] : 0.f;
        #pragma unroll
        for (int mi=0;mi<4;++mi){
            const int row = m0 + wm + mi*16 + quad*4;
            #pragma unroll
            for (int r=0;r<4;++r)
                C[(size_t)(row+r)*N + col] = acc[mi][ni][r] + bv;
        }
    }
}

extern "C" void kernel_launch(void* const* d_in, const int* in_sizes, int n_in,
                              void* d_out, int out_size, void* d_ws, size_t ws_size,
                              hipStream_t stream)
{
    const float* x  = (const float*)d_in[0];
    const float* Wq = (const float*)d_in[1];
    const float* Wk = (const float*)d_in[2];
    const float* Wv = (const float*)d_in[3];
    const float* Wp = (const float*)d_in[4];
    const float* bp = (const float*)d_in[5];
    float* out = (float*)d_out;

    // workspace layout (134.2 MB, round-4 proven footprint)
    float* q   = (float*)d_ws;                 // [BT][1024] f32
    u16*  kh   = (u16*)(q + (size_t)BT*D_);    // [BT][1024] u16
    u16*  kl   = kh + (size_t)BT*D_;
    u16*  vth  = kl + (size_t)BT*D_;           // [64bh][64e][2048t] u16
    u16*  vtl  = vth + (size_t)BT*D_;
    float* att = (float*)(vtl + (size_t)BT*D_);// [BT][1024] f32
    // Wt (split) aliases the att region: dead before attn writes att
    u16*  Wth  = (u16*)att;                    // [3072][1024] u16 (6.3 MB)
    u16*  Wtl  = Wth + (size_t)3072*D_;

    pack_w  <<<dim3(16,16,3), 256, 0, stream>>>(Wq, Wk, Wv, Wth, Wtl);
    gemm_qkv<<<dim3(24, BT/128), 256, 0, stream>>>(x, Wth, Wtl, q, kh, kl, vth, vtl);
    attn    <<<dim3(8, 128), 256, 0, stream>>>(q, kh, kl, vth, vtl, att);
    gemm_bt <<<dim3(8, BT/128), 256, 0, stream>>>(att, Wp, out, bp, BT, D_, D_);
}

// Round 10
// 469.296 us; speedup vs baseline: 1.4048x; 1.0479x over previous
//
#include <hip/hip_runtime.h>
#include <hip/hip_bf16.h>

typedef unsigned short u16;
typedef unsigned int u32;
typedef __attribute__((ext_vector_type(8))) short short8;
typedef __attribute__((ext_vector_type(4))) float f32x4;

#define B_ 4
#define T_ 2048
#define D_ 1024
#define H_ 16
#define HS_ 64
#define BT (B_*T_)

__device__ __forceinline__ float bf2f(u16 b){ union{u32 u; float f;} v; v.u=((u32)b)<<16; return v.f; }
__device__ __forceinline__ u16 f2bf(float f){
    __hip_bfloat16 h = __float2bfloat16(f);
    union{__hip_bfloat16 h; u16 u;} v; v.h = h; return v.u;
}
// split f32 into hi/lo bf16: x ~= hi + lo
__device__ __forceinline__ void split2(float x, u16& h, u16& l){
    u16 hb = f2bf(x);
    float fh = bf2f(hb);
    h = hb; l = f2bf(x - fh);
}
union U4 { u16 s[4]; uint2 v; };
union S8 { u16 s[8]; short8 v; };

// async global->LDS, 16B per lane; LDS dest wave-linear (base + lane*16)
#define GLD16(g,l) __builtin_amdgcn_global_load_lds( \
    (__attribute__((address_space(1))) void*)(u16*)(g), \
    (__attribute__((address_space(3))) void*)(l), 16, 0, 0)

// XOR-swizzled offset into a row-major [R][64]-u16 LDS tile, 16B-chunk granularity.
// Conflict-free with the t>>3 staging pattern (r5: SQ_LDS_BANK_CONFLICT == 0).
__device__ __forceinline__ int swz(int row, int col){
    return row*64 + (((col>>3) ^ (row&7))<<3) + (col&7);
}
// chunk-swizzle for the GEMM [128][32]-u16 tiles (64B rows, 4 x 16B chunks).
// Proven: SQ_LDS_BANK_CONFLICT 12.6M -> 0 (round 4).
#define FCHK(r) (((r)>>1)&3)

// ---- pack: Wt[n][d] (split hi/lo) = W_z[h][d][e], n = z*1024 + h*64 + e ----
__global__ __launch_bounds__(256) void pack_w(const float* __restrict__ Wq,
                                              const float* __restrict__ Wk,
                                              const float* __restrict__ Wv,
                                              u16* __restrict__ Wth,
                                              u16* __restrict__ Wtl)
{
    __shared__ float Tl[64*68];
    const int h = blockIdx.x, dt = blockIdx.y, z = blockIdx.z;
    const float* src = (z==0) ? Wq : ((z==1) ? Wk : Wv);
    const int t = threadIdx.x;
    const int d0 = dt*64;
    #pragma unroll
    for (int i=0;i<4;++i){
        int ci = t + 256*i;
        int dr = ci>>4, ec = ci&15;
        float4 v = *(const float4*)(src + ((size_t)h*D_ + d0+dr)*HS_ + ec*4);
        *(float4*)(Tl + dr*68 + ec*4) = v;
    }
    __syncthreads();
    #pragma unroll
    for (int i=0;i<4;++i){
        int ci = t + 256*i;
        int e = ci>>4, dc = ci&15;
        U4 hh, ll;
        #pragma unroll
        for (int j=0;j<4;++j){
            float f = Tl[(dc*4+j)*68 + e];
            split2(f, hh.s[j], ll.s[j]);
        }
        int n = z*D_ + h*HS_ + e;
        *(uint2*)(Wth + (size_t)n*D_ + d0 + dc*4) = hh.v;
        *(uint2*)(Wtl + (size_t)n*D_ + d0 + dc*4) = ll.v;
    }
}

// ---- QKV GEMM: qkv[t][col] = x[t][:]·Wt[col][:], col in [0,3072) ----
// LDS chunk-swizzled (FCHK): B via pre-swizzled GLOBAL source, A via swizzled ds_write.
__global__ __launch_bounds__(256) void gemm_qkv(const float* __restrict__ x,
                                                const u16* __restrict__ Wth,
                                                const u16* __restrict__ Wtl,
                                                float* __restrict__ qo,
                                                u16* __restrict__ kho, u16* __restrict__ klo,
                                                u16* __restrict__ vth, u16* __restrict__ vtl)
{
    __shared__ u16 Ash[128*32], Asl[128*32];
    __shared__ u16 Bsh[128*32], Bsl[128*32];
    const int n0 = blockIdx.x*128, m0 = blockIdx.y*128;
    const int t = threadIdx.x;
    const int w = t>>6, lane = t&63, quad = lane>>4, l16 = lane&15;
    const int wm = (w>>1)*64, wn = (w&1)*64;
    f32x4 acc[4][4];
    #pragma unroll
    for (int i=0;i<4;++i)
        #pragma unroll
        for (int j=0;j<4;++j) acc[i][j] = (f32x4){0.f,0.f,0.f,0.f};
    for (int kt=0; kt<32; ++kt){
        const int k0 = kt*32;
        #pragma unroll
        for (int i=0;i<2;++i){           // B: async 16B chunks, pre-swizzled source
            int ci = t + 256*i;
            int row = ci>>2, c = ci&3;
            int cs = c ^ FCHK(row);
            GLD16(Wth + (size_t)(n0+row)*D_ + k0 + cs*8, Bsh + ci*8);
            GLD16(Wtl + (size_t)(n0+row)*D_ + k0 + cs*8, Bsl + ci*8);
        }
        #pragma unroll
        for (int i=0;i<4;++i){           // A: f32 load + split, swizzled ds_write
            int ci = t + 256*i;
            int row = ci>>3, c4 = ci&7;
            float4 av = *(const float4*)(x + (size_t)(m0+row)*D_ + k0 + c4*4);
            U4 hh, ll;
            split2(av.x, hh.s[0], ll.s[0]); split2(av.y, hh.s[1], ll.s[1]);
            split2(av.z, hh.s[2], ll.s[2]); split2(av.w, hh.s[3], ll.s[3]);
            int off = row*32 + ((((c4>>1) ^ FCHK(row))<<3) | ((c4&1)<<2));
            *(uint2*)(Ash + off) = hh.v;
            *(uint2*)(Asl + off) = ll.v;
        }
        __syncthreads();
        short8 afh[4], afl[4], bfh[4], bfl[4];
        #pragma unroll
        for (int mi=0;mi<4;++mi){
            const int rr = wm+mi*16+l16;
            const int off = rr*32 + ((quad ^ FCHK(rr))<<3);
            afh[mi] = *(const short8*)(Ash + off);
            afl[mi] = *(const short8*)(Asl + off);
        }
        #pragma unroll
        for (int ni=0;ni<4;++ni){
            const int rr = wn+ni*16+l16;
            const int off = rr*32 + ((quad ^ FCHK(rr))<<3);
            bfh[ni] = *(const short8*)(Bsh + off);
            bfl[ni] = *(const short8*)(Bsl + off);
        }
        #pragma unroll
        for (int mi=0;mi<4;++mi)
            #pragma unroll
            for (int ni=0;ni<4;++ni){
                acc[mi][ni] = __builtin_amdgcn_mfma_f32_16x16x32_bf16(afh[mi], bfh[ni], acc[mi][ni], 0,0,0);
                acc[mi][ni] = __builtin_amdgcn_mfma_f32_16x16x32_bf16(afh[mi], bfl[ni], acc[mi][ni], 0,0,0);
                acc[mi][ni] = __builtin_amdgcn_mfma_f32_16x16x32_bf16(afl[mi], bfh[ni], acc[mi][ni], 0,0,0);
            }
        __syncthreads();
    }
    const int z = n0 >> 10;              // block-uniform (128 | 1024)
    if (z == 0){
        #pragma unroll
        for (int ni=0;ni<4;++ni){
            const int nloc = (n0 & 1023) + wn + ni*16 + l16;
            #pragma unroll
            for (int mi=0;mi<4;++mi){
                const int row = m0 + wm + mi*16 + quad*4;
                #pragma unroll
                for (int r=0;r<4;++r)
                    qo[(size_t)(row+r)*D_ + nloc] = acc[mi][ni][r];
            }
        }
    } else if (z == 1){
        #pragma unroll
        for (int ni=0;ni<4;++ni){
            const int nloc = (n0 & 1023) + wn + ni*16 + l16;
            #pragma unroll
            for (int mi=0;mi<4;++mi){
                const int row = m0 + wm + mi*16 + quad*4;
                #pragma unroll
                for (int r=0;r<4;++r){
                    u16 hh, ll; split2(acc[mi][ni][r], hh, ll);
                    kho[(size_t)(row+r)*D_ + nloc] = hh;
                    klo[(size_t)(row+r)*D_ + nloc] = ll;
                }
            }
        }
    } else {
        #pragma unroll
        for (int ni=0;ni<4;++ni){
            const int nloc = (n0 & 1023) + wn + ni*16 + l16;
            const int hloc = nloc>>6, e = nloc&63;
            #pragma unroll
            for (int mi=0;mi<4;++mi){
                const int rowb = m0 + wm + mi*16 + quad*4;   // multiple of 4
                const int bidx = rowb >> 11, tloc = rowb & 2047;
                U4 hh, ll;
                #pragma unroll
                for (int r=0;r<4;++r) split2(acc[mi][ni][r], hh.s[r], ll.s[r]);
                const size_t adr = ((size_t)((bidx*16 + hloc)*64 + e))*T_ + tloc;
                *(uint2*)(vth + adr) = hh.v;
                *(uint2*)(vtl + adr) = ll.v;
            }
        }
    }
}

// ---- causal flash attention, ROUND-10: GLD16 double-buffered K/V staging,
// ONE barrier per kv-tile (was 2). Staging goes global->LDS via DMA with
// pre-swizzled SOURCE (rule: linear dest + inverse-swz source + swz read —
// proven in gemm_qkv's B path), eliminating the 8-uint4 register prefetch
// (-32 VGPR) and all staging ds_writes. Loads for tile t+1 are issued right
// after the barrier and drained by the NEXT barrier's vmcnt(0) — a full
// compute phase of latency hiding. Race-safe: readers of buf[cur^1] all
// finished before the barrier that precedes the issue.
// Shell: 8-wave blocks / 128-row q-tiles (r5 pairing: block x does qi=15-x
// then x, 34 tile-units each; r8 proved 4- vs 8-wave neutral), grid (8,64),
// XCD grouping (same-bh blocks share L%8=bx), LDS 80 KB -> 2 blocks/CU =
// 16 waves/CU. Inner loop = r9's swapped-QK^T (proven). launch_bounds(512,2):
// cap = 256/arg2 = 128 VGPR (model fits r1/r3/r7 evidence). ----
__global__ __launch_bounds__(512, 2) void attn(const float* __restrict__ qf,
                                            const u16* __restrict__ kh, const u16* __restrict__ kl,
                                            const u16* __restrict__ vth, const u16* __restrict__ vtl,
                                            float* __restrict__ att)
{
    __shared__ u16 KshH[2*64*64], KshL[2*64*64];   // dbuf [kv][e], swizzled (32 KB)
    __shared__ u16 VshH[2*64*64], VshL[2*64*64];   // dbuf [e][kv], swizzled (32 KB)
    __shared__ u16 Pb[8*16*64];                    // per-wave [16][64], phased h/l (16 KB)
    const int x = blockIdx.y & 7;            // q-pair index (XCD-grouped remap, r3-proven)
    const int bh = (blockIdx.x << 3) | (blockIdx.y >> 3);
    const int b = bh >> 4, h = bh & 15;
    const int t = threadIdx.x;
    const int w = t>>6, lane = t&63, quad = lane>>4, l16 = lane&15;

    u16* Pm = Pb + w*1024;

    // staging geometry: 512 threads x 1 GLD16 per array = 8 KB/array/tile.
    // LDS dest linear (t*16B); global source chunk pre-swizzled to match swz().
    const int srow = t>>3;                   // row 0..63 (K: kv, V: e)
    const int csrc = (t&7) ^ (srow&7);       // inverse-swz source chunk
    const int ldst = t*8;                    // u16 offset of this thread's 16B slot

    #define STAGE_KV(kvbase, bsel) do{                                         \
        const size_t gk_ = ((size_t)(b*T_ + (kvbase) + srow))*D_ + h*64 + csrc*8; \
        GLD16(kh  + gk_, KshH + (bsel)*4096 + ldst);                           \
        GLD16(kl  + gk_, KshL + (bsel)*4096 + ldst);                           \
        const size_t gv_ = ((size_t)(bh*64 + srow))*T_ + (kvbase) + csrc*8;    \
        GLD16(vth + gv_, VshH + (bsel)*4096 + ldst);                           \
        GLD16(vtl + gv_, VshL + (bsel)*4096 + ldst);                           \
    }while(0)

    int cur = 0;
    STAGE_KV(0, 0);                          // prologue: tile 0 -> buf 0

    #pragma unroll 1
    for (int seg=0; seg<2; ++seg){
        const int qi = seg ? x : (15 - x);   // heavy segment first
        const int qrow = qi*128 + w*16;      // wave's absolute q base
        const int q_abs = qrow + l16;        // this lane's q row (swapped layout)

        short8 qh_[2], ql_[2];
        {
            const float* qp = qf + ((size_t)(b*T_ + qrow + l16))*D_ + h*64;
            #pragma unroll
            for (int ks=0;ks<2;++ks){
                float4 a0 = *(const float4*)(qp + ks*32 + quad*8);
                float4 a1 = *(const float4*)(qp + ks*32 + quad*8 + 4);
                S8 hh, ll;
                split2(a0.x, hh.s[0], ll.s[0]); split2(a0.y, hh.s[1], ll.s[1]);
                split2(a0.z, hh.s[2], ll.s[2]); split2(a0.w, hh.s[3], ll.s[3]);
                split2(a1.x, hh.s[4], ll.s[4]); split2(a1.y, hh.s[5], ll.s[5]);
                split2(a1.z, hh.s[6], ll.s[6]); split2(a1.w, hh.s[7], ll.s[7]);
                qh_[ks] = hh.v; ql_[ks] = ll.v;
            }
        }
        f32x4 o[4];
        #pragma unroll
        for (int i=0;i<4;++i) o[i] = (f32x4){0.f,0.f,0.f,0.f};
        float m_i = -INFINITY, l_i = 0.f;    // scalar state: one q per lane

        const int kvT = 2*qi + 2;
        for (int kvt=0; kvt<kvT; ++kvt){
            __syncthreads();                 // drains buf[cur] loads; prev readers of buf[cur^1] done
            // issue next-tile loads into the other buffer (drained at next barrier)
            const int nk = (kvt+1 < kvT) ? (kvt+1) : ((seg==0) ? 0 : -1);
            if (nk >= 0) STAGE_KV(nk*64, cur^1);

            const u16* KH = KshH + cur*4096;
            const u16* KL = KshL + cur*4096;
            const u16* VH = VshH + cur*4096;
            const u16* VL = VshL + cur*4096;

            // ---- QK^T, SWAPPED: mfma(A=K, B=Q). lane holds q = l16 (col),
            // kv = ni*16 + quad*4 + r (row). ----
            float s[4][4];
            __builtin_amdgcn_s_setprio(1);
            #pragma unroll
            for (int ni=0;ni<4;++ni){
                f32x4 sa = (f32x4){0.f,0.f,0.f,0.f};
                const int row = ni*16 + l16;
                #pragma unroll
                for (int ks=0;ks<2;++ks){
                    const int co = swz(row, ks*32 + quad*8);
                    short8 k8h = *(const short8*)(KH + co);
                    short8 k8l = *(const short8*)(KL + co);
                    sa = __builtin_amdgcn_mfma_f32_16x16x32_bf16(k8h, qh_[ks], sa, 0,0,0);
                    sa = __builtin_amdgcn_mfma_f32_16x16x32_bf16(k8l, qh_[ks], sa, 0,0,0);
                    sa = __builtin_amdgcn_mfma_f32_16x16x32_bf16(k8h, ql_[ks], sa, 0,0,0);
                }
                #pragma unroll
                for (int r=0;r<4;++r) s[ni][r] = sa[r]*0.125f;
            }
            __builtin_amdgcn_s_setprio(0);
            // causal mask: kv > q
            if (kvt*64 + 63 > qrow){
                #pragma unroll
                for (int ni=0;ni<4;++ni){
                    #pragma unroll
                    for (int r=0;r<4;++r){
                        const int kv_abs = kvt*64 + ni*16 + quad*4 + r;
                        if (kv_abs > q_abs) s[ni][r] = -INFINITY;
                    }
                }
            }
            // ---- online softmax, lane-local row + 2-step cross-quad reduce ----
            float rm = s[0][0];
            #pragma unroll
            for (int ni=0;ni<4;++ni)
                #pragma unroll
                for (int r=0;r<4;++r) rm = fmaxf(rm, s[ni][r]);
            rm = fmaxf(rm, __shfl_xor(rm, 16));
            rm = fmaxf(rm, __shfl_xor(rm, 32));
            const float mnew = fmaxf(m_i, rm);
            const float alpha = __expf(m_i - mnew);
            m_i = mnew;
            float rs = 0.f;
            #pragma unroll
            for (int ni=0;ni<4;++ni)
                #pragma unroll
                for (int r=0;r<4;++r){
                    s[ni][r] = __expf(s[ni][r] - mnew);
                    rs += s[ni][r];
                }
            rs += __shfl_xor(rs, 16);
            rs += __shfl_xor(rs, 32);
            l_i = l_i*alpha + rs;
            // broadcast alpha for the o-rescale (o rows are q = quad*4+r)
            float a4[4];
            #pragma unroll
            for (int r=0;r<4;++r) a4[r] = __shfl(alpha, quad*4 + r);
            #pragma unroll
            for (int ni=0;ni<4;++ni)
                #pragma unroll
                for (int r=0;r<4;++r) o[ni][r] *= a4[r];

            // ---- P: split once; phased h then l; b64 writes (4 consecutive kv) ----
            uint2 plv[4];
            #pragma unroll
            for (int ni=0;ni<4;++ni){
                U4 hh, ll;
                #pragma unroll
                for (int r=0;r<4;++r) split2(s[ni][r], hh.s[r], ll.s[r]);
                *(uint2*)(Pm + swz(l16, ni*16 + quad*4)) = hh.v;
                plv[ni] = ll.v;
            }
            __asm__ volatile("s_waitcnt lgkmcnt(0)" ::: "memory");
            short8 pah[2], pal[2];
            #pragma unroll
            for (int ks=0;ks<2;++ks)
                pah[ks] = *(const short8*)(Pm + swz(l16, ks*32 + quad*8));
            __asm__ volatile("" ::: "memory");   // keep reads before the l-overwrite
            #pragma unroll
            for (int ni=0;ni<4;++ni)
                *(uint2*)(Pm + swz(l16, ni*16 + quad*4)) = plv[ni];
            __asm__ volatile("s_waitcnt lgkmcnt(0)" ::: "memory");
            #pragma unroll
            for (int ks=0;ks<2;++ks)
                pal[ks] = *(const short8*)(Pm + swz(l16, ks*32 + quad*8));
            __asm__ volatile("" ::: "memory");   // keep reads before next-iter overwrite

            __builtin_amdgcn_s_setprio(1);
            #pragma unroll
            for (int ni=0;ni<4;++ni){
                const int row = ni*16 + l16;
                #pragma unroll
                for (int ks=0;ks<2;++ks){
                    const int co = swz(row, ks*32 + quad*8);
                    short8 v8h = *(const short8*)(VH + co);
                    short8 v8l = *(const short8*)(VL + co);
                    o[ni] = __builtin_amdgcn_mfma_f32_16x16x32_bf16(pah[ks], v8h, o[ni], 0,0,0);
                    o[ni] = __builtin_amdgcn_mfma_f32_16x16x32_bf16(pah[ks], v8l, o[ni], 0,0,0);
                    o[ni] = __builtin_amdgcn_mfma_f32_16x16x32_bf16(pal[ks], v8h, o[ni], 0,0,0);
                }
            }
            __builtin_amdgcn_s_setprio(0);
            cur ^= 1;
        }
        // epilogue: o rows are q = quad*4+r; l_i identical across quads per l16
        float lt[4];
        #pragma unroll
        for (int r=0;r<4;++r) lt[r] = __shfl(l_i, quad*4 + r);
        const size_t ob = (size_t)(b*T_ + qrow);
        #pragma unroll
        for (int ni=0;ni<4;++ni){
            const int col = h*64 + ni*16 + l16;
            #pragma unroll
            for (int r=0;r<4;++r)
                att[(ob + quad*4 + r)*D_ + col] = o[ni][r] / lt[r];
        }
    }
    #undef STAGE_KV
}

// ---- f32-in GEMM (A f32, Bt f32 [N,K], bias) for out-proj; chunk-swizzled LDS ----
__global__ __launch_bounds__(256) void gemm_bt(const float* __restrict__ A,
                                               const float* __restrict__ Bt,
                                               float* __restrict__ C,
                                               const float* __restrict__ bias,
                                               int M, int N, int K)
{
    __shared__ u16 Ash[128*32], Asl[128*32];
    __shared__ u16 Bsh[128*32], Bsl[128*32];
    const int n0 = blockIdx.x*128, m0 = blockIdx.y*128;
    const int t = threadIdx.x;
    const int w = t>>6, lane = t&63, quad = lane>>4, l16 = lane&15;
    const int wm = (w>>1)*64, wn = (w&1)*64;
    f32x4 acc[4][4];
    #pragma unroll
    for (int i=0;i<4;++i)
        #pragma unroll
        for (int j=0;j<4;++j) acc[i][j] = (f32x4){0.f,0.f,0.f,0.f};
    const int kT = K >> 5;
    for (int kt=0; kt<kT; ++kt){
        const int k0 = kt*32;
        #pragma unroll
        for (int i=0;i<4;++i){
            int ci = t + 256*i;
            int row = ci>>3, c4 = ci&7;
            float4 av = *(const float4*)(A  + (size_t)(m0+row)*K + k0 + c4*4);
            float4 bv = *(const float4*)(Bt + (size_t)(n0+row)*K + k0 + c4*4);
            U4 ah, al, bh, bl;
            split2(av.x, ah.s[0], al.s[0]); split2(av.y, ah.s[1], al.s[1]);
            split2(av.z, ah.s[2], al.s[2]); split2(av.w, ah.s[3], al.s[3]);
            split2(bv.x, bh.s[0], bl.s[0]); split2(bv.y, bh.s[1], bl.s[1]);
            split2(bv.z, bh.s[2], bl.s[2]); split2(bv.w, bh.s[3], bl.s[3]);
            int off = row*32 + ((((c4>>1) ^ FCHK(row))<<3) | ((c4&1)<<2));
            *(uint2*)(Ash + off) = ah.v;
            *(uint2*)(Asl + off) = al.v;
            *(uint2*)(Bsh + off) = bh.v;
            *(uint2*)(Bsl + off) = bl.v;
        }
        __syncthreads();
        short8 afh[4], afl[4], bfh[4], bfl[4];
        #pragma unroll
        for (int mi=0;mi<4;++mi){
            const int rr = wm+mi*16+l16;
            const int off = rr*32 + ((quad ^ FCHK(rr))<<3);
            afh[mi] = *(const short8*)(Ash + off);
            afl[mi] = *(const short8*)(Asl + off);
        }
        #pragma unroll
        for (int ni=0;ni<4;++ni){
            const int rr = wn+ni*16+l16;
            const int off = rr*32 + ((quad ^ FCHK(rr))<<3);
            bfh[ni] = *(const short8*)(Bsh + off);
            bfl[ni] = *(const short8*)(Bsl + off);
        }
        #pragma unroll
        for (int mi=0;mi<4;++mi)
            #pragma unroll
            for (int ni=0;ni<4;++ni){
                acc[mi][ni] = __builtin_amdgcn_mfma_f32_16x16x32_bf16(afh[mi], bfh[ni], acc[mi][ni], 0,0,0);
                acc[mi][ni] = __builtin_amdgcn_mfma_f32_16x16x32_bf16(afh[mi], bfl[ni], acc[mi][ni], 0,0,0);
                acc[mi][ni] = __builtin_amdgcn_mfma_f32_16x16x32_bf16(afl[mi], bfh[ni], acc[mi][ni], 0,0,0);
            }
        __syncthreads();
    }
    #pragma unroll
    for (int ni=0;ni<4;++ni){
        const int col = n0 + wn + ni*16 + l16;
        const float bv = bias ? bias[col] : 0.f;
        #pragma unroll
        for (int mi=0;mi<4;++mi){
            const int row = m0 + wm + mi*16 + quad*4;
            #pragma unroll
            for (int r=0;r<4;++r)
                C[(size_t)(row+r)*N + col] = acc[mi][ni][r] + bv;
        }
    }
}

extern "C" void kernel_launch(void* const* d_in, const int* in_sizes, int n_in,
                              void* d_out, int out_size, void* d_ws, size_t ws_size,
                              hipStream_t stream)
{
    const float* x  = (const float*)d_in[0];
    const float* Wq = (const float*)d_in[1];
    const float* Wk = (const float*)d_in[2];
    const float* Wv = (const float*)d_in[3];
    const float* Wp = (const float*)d_in[4];
    const float* bp = (const float*)d_in[5];
    float* out = (float*)d_out;

    // workspace layout (134.2 MB, round-4 proven footprint)
    float* q   = (float*)d_ws;                 // [BT][1024] f32
    u16*  kh   = (u16*)(q + (size_t)BT*D_);    // [BT][1024] u16
    u16*  kl   = kh + (size_t)BT*D_;
    u16*  vth  = kl + (size_t)BT*D_;           // [64bh][64e][2048t] u16
    u16*  vtl  = vth + (size_t)BT*D_;
    float* att = (float*)(vtl + (size_t)BT*D_);// [BT][1024] f32
    // Wt (split) aliases the att region: dead before attn writes att
    u16*  Wth  = (u16*)att;                    // [3072][1024] u16 (6.3 MB)
    u16*  Wtl  = Wth + (size_t)3072*D_;

    pack_w  <<<dim3(16,16,3), 256, 0, stream>>>(Wq, Wk, Wv, Wth, Wtl);
    gemm_qkv<<<dim3(24, BT/128), 256, 0, stream>>>(x, Wth, Wtl, q, kh, kl, vth, vtl);
    attn    <<<dim3(8, 64), 512, 0, stream>>>(q, kh, kl, vth, vtl, att);
    gemm_bt <<<dim3(8, BT/128), 256, 0, stream>>>(att, Wp, out, bp, BT, D_, D_);
}